// Round 1
// baseline (2872.332 us; speedup 1.0000x reference)
//
#include <hip/hip_runtime.h>
#include <math.h>

#define N0 50000
#define N1 12500
#define N2 3125
#define NNZ 200000

// ---------------- scatter kernels (segment_sum via atomics) ----------------

__global__ void scatter6(const float* __restrict__ x, const int* __restrict__ src,
                         const int* __restrict__ dst, float* __restrict__ agg, int E) {
    int e = blockIdx.x * blockDim.x + threadIdx.x;
    if (e >= E) return;
    int s = src[e], d = dst[e];
#pragma unroll
    for (int f = 0; f < 6; f++) atomicAdd(&agg[d * 6 + f], x[s * 6 + f]);
}

// 32 threads per edge, 4 floats each (128 features)
__global__ void scatterH(const float* __restrict__ h, const int* __restrict__ src,
                         const int* __restrict__ dst, float* __restrict__ agg, int E) {
    int t = blockIdx.x * blockDim.x + threadIdx.x;
    int e = t >> 5;
    int lane = t & 31;
    if (e >= E) return;
    int s = src[e], d = dst[e];
    float4 v = ((const float4*)(h + (size_t)s * 128))[lane];
    float* ap = agg + (size_t)d * 128 + lane * 4;
    atomicAdd(ap + 0, v.x);
    atomicAdd(ap + 1, v.y);
    atomicAdd(ap + 2, v.z);
    atomicAdd(ap + 3, v.w);
}

// i_out[rows[k], f] += vals[k] * e[cols[k], f], f in [0,96)
__global__ void interp_scatter(const float* __restrict__ e, const int* __restrict__ rows,
                               const int* __restrict__ cols, const float* __restrict__ vals,
                               float* __restrict__ outb, int nnz) {
    int t = blockIdx.x * blockDim.x + threadIdx.x;
    int k = t / 96;
    int f = t % 96;
    if (k >= nnz) return;
    atomicAdd(&outb[rows[k] * 96 + f], vals[k] * e[cols[k] * 96 + f]);
}

// ---------------- generic dual-input GEMM ----------------
// C[m,j] = act( sum_k A1[m,k]*W1[k,j] + sum_k A2[m,k]*W2[k,j] + bias[j] )
// A1: M x K1, A2: M x K2 (K2 may be 0). Row-major everywhere.
// ACT: 0 = none, 1 = relu. Tile 64x64, BK=16, 256 threads, 4x4/thread.
template <int ACT>
__global__ __launch_bounds__(256) void dualgemm(
        const float* __restrict__ A1, const float* __restrict__ A2,
        const float* __restrict__ W1, const float* __restrict__ W2,
        const float* __restrict__ bias, float* __restrict__ C,
        int M, int K1, int K2, int J) {
    const int BM = 64, BN = 64, BK = 16;
    __shared__ float As[BK][BM + 1];   // +1 pad: avoid 16-way bank conflict on store
    __shared__ float Ws[BK][BN];
    int m0 = blockIdx.x * BM;
    int n0 = blockIdx.y * BN;
    int tid = threadIdx.x;
    int tm = tid >> 4, tn = tid & 15;
    int Ktot = K1 + K2;
    float acc[4][4] = {};
    for (int kt = 0; kt < Ktot; kt += BK) {
        // A tile: 64 rows x 16 k
#pragma unroll
        for (int q = 0; q < 4; q++) {
            int idx = tid + q * 256;
            int row = idx >> 4;
            int kk = idx & 15;
            int m = m0 + row, k = kt + kk;
            float v = 0.f;
            if (m < M && k < Ktot)
                v = (k < K1) ? A1[(size_t)m * K1 + k] : A2[(size_t)m * K2 + (k - K1)];
            As[kk][row] = v;
        }
        // W tile: 16 k x 64 n
#pragma unroll
        for (int q = 0; q < 4; q++) {
            int idx = tid + q * 256;
            int kk = idx >> 6;
            int n = idx & 63;
            int k = kt + kk, nn = n0 + n;
            float v = 0.f;
            if (k < Ktot && nn < J)
                v = (k < K1) ? W1[(size_t)k * J + nn] : W2[(size_t)(k - K1) * J + nn];
            Ws[kk][n] = v;
        }
        __syncthreads();
#pragma unroll
        for (int k = 0; k < BK; k++) {
            float av[4], wv[4];
#pragma unroll
            for (int i = 0; i < 4; i++) av[i] = As[k][tm * 4 + i];
#pragma unroll
            for (int j = 0; j < 4; j++) wv[j] = Ws[k][tn * 4 + j];
#pragma unroll
            for (int i = 0; i < 4; i++)
#pragma unroll
                for (int j = 0; j < 4; j++) acc[i][j] += av[i] * wv[j];
        }
        __syncthreads();
    }
#pragma unroll
    for (int i = 0; i < 4; i++) {
        int m = m0 + tm * 4 + i;
        if (m >= M) continue;
#pragma unroll
        for (int j = 0; j < 4; j++) {
            int n = n0 + tn * 4 + j;
            if (n >= J) continue;
            float v = acc[i][j] + bias[n];
            if (ACT == 1) v = fmaxf(v, 0.f);
            C[(size_t)m * J + n] = v;
        }
    }
}

// ---------------- decoder ----------------
// One 64-lane wave per (node, channel i). lane -> hidden unit.
// v[96] = [e0[n, 32i..], i1[n, 32i..], i2[n, 32i..]]
// h = elu(v @ W0[i] + b0[i]); out[n*3+i] = h . Wout[i] + bout[i]
__global__ __launch_bounds__(256) void decoder(
        const float* __restrict__ e0, const float* __restrict__ i1,
        const float* __restrict__ i2, const float* __restrict__ W0,
        const float* __restrict__ b0, const float* __restrict__ Wout,
        const float* __restrict__ bout, float* __restrict__ out, int N) {
    int ch = blockIdx.y;  // 0..2
    __shared__ float sW[96 * 64];
    __shared__ float sWout[64];
    __shared__ float sb0[64];
    __shared__ float sbout;
    for (int q = threadIdx.x; q < 96 * 64; q += blockDim.x) sW[q] = W0[ch * 96 * 64 + q];
    if (threadIdx.x < 64) {
        sWout[threadIdx.x] = Wout[ch * 64 + threadIdx.x];
        sb0[threadIdx.x] = b0[ch * 64 + threadIdx.x];
    }
    if (threadIdx.x == 0) sbout = bout[ch];
    __syncthreads();
    int lane = threadIdx.x & 63;
    int wave = threadIdx.x >> 6;
    int wavesTotal = gridDim.x * (blockDim.x >> 6);
    for (int n = blockIdx.x * (blockDim.x >> 6) + wave; n < N; n += wavesTotal) {
        const float* pe0 = e0 + (size_t)n * 96 + ch * 32;
        const float* pi1 = i1 + (size_t)n * 96 + ch * 32;
        const float* pi2 = i2 + (size_t)n * 96 + ch * 32;
        float acc = sb0[lane];
#pragma unroll
        for (int f = 0; f < 32; f++) acc += pe0[f] * sW[f * 64 + lane];
#pragma unroll
        for (int f = 0; f < 32; f++) acc += pi1[f] * sW[(32 + f) * 64 + lane];
#pragma unroll
        for (int f = 0; f < 32; f++) acc += pi2[f] * sW[(64 + f) * 64 + lane];
        float h = acc > 0.f ? acc : (expf(acc) - 1.0f);  // ELU alpha=1
        float p = h * sWout[lane];
#pragma unroll
        for (int off = 32; off > 0; off >>= 1) p += __shfl_down(p, off, 64);
        if (lane == 0) out[(size_t)n * 3 + ch] = p + sbout;
    }
}

// ---------------- host launch ----------------

extern "C" void kernel_launch(void* const* d_in, const int* in_sizes, int n_in,
                              void* d_out, int out_size, void* d_ws, size_t ws_size,
                              hipStream_t stream) {
    const float* x0 = (const float*)d_in[0];
    const float* x1 = (const float*)d_in[1];
    const float* x2 = (const float*)d_in[2];
    const int* ei0 = (const int*)d_in[3];
    const int* ei1 = (const int*)d_in[4];
    const int* ei2 = (const int*)d_in[5];
    const int* A1r = (const int*)d_in[6];
    const int* A1c = (const int*)d_in[7];
    const float* A1v = (const float*)d_in[8];
    const int* A2r = (const int*)d_in[9];
    const int* A2c = (const int*)d_in[10];
    const float* A2v = (const float*)d_in[11];
    const float* c1Wrel = (const float*)d_in[12];
    const float* c1brel = (const float*)d_in[13];
    const float* c1Wroot = (const float*)d_in[14];
    const float* c2Wrel = (const float*)d_in[15];
    const float* c2brel = (const float*)d_in[16];
    const float* c2Wroot = (const float*)d_in[17];
    const float* linW = (const float*)d_in[18];
    const float* linb = (const float*)d_in[19];
    const float* dW0 = (const float*)d_in[20];
    const float* db0 = (const float*)d_in[21];
    const float* dWout = (const float*)d_in[22];
    const float* dbout = (const float*)d_in[23];
    float* out = (float*)d_out;

    // workspace layout (floats): pools reused; i1/i2 overlay h1/agg after encoders
    float* ws = (float*)d_ws;
    float* h1 = ws;                  // 6.4M floats (N0*128)
    float* agg = ws + 6400000;       // 6.4M
    float* h2 = ws + 12800000;       // 6.4M
    float* e0 = ws + 19200000;       // 4.8M (N0*96)
    float* e1 = ws + 24000000;       // 1.2M
    float* e2 = ws + 25200000;       // 0.3M
    float* i1 = ws;                  // reuse (4.8M), valid after encoder phase
    float* i2 = ws + 4800000;        // reuse (4.8M)
    // total: 25.5M floats = 102 MB

    const float* xs[3] = {x0, x1, x2};
    const int* eis[3] = {ei0, ei1, ei2};
    const int Ns[3] = {N0, N1, N2};
    const int Es[3] = {800000, 200000, 50000};
    float* es[3] = {e0, e1, e2};

    for (int i = 0; i < 3; i++) {
        int N = Ns[i], E = Es[i];
        const float* x = xs[i];
        const int* src = eis[i];
        const int* dst = eis[i] + E;

        // conv1: agg6 = segment_sum(x[src], dst); h1 = relu(agg6@Wrel + brel + x@Wroot)
        hipMemsetAsync(agg, 0, (size_t)N * 6 * sizeof(float), stream);
        scatter6<<<(E + 255) / 256, 256, 0, stream>>>(x, src, dst, agg, E);
        dim3 g1((N + 63) / 64, 2);
        dualgemm<1><<<g1, 256, 0, stream>>>(agg, x, c1Wrel + i * 6 * 128,
                                            c1Wroot + i * 6 * 128, c1brel + i * 128,
                                            h1, N, 6, 6, 128);

        // conv2: agg128 = segment_sum(h1[src], dst); h2 = relu(agg@Wrel + brel + h1@Wroot)
        hipMemsetAsync(agg, 0, (size_t)N * 128 * sizeof(float), stream);
        scatterH<<<((size_t)E * 32 + 255) / 256, 256, 0, stream>>>(h1, src, dst, agg, E);
        dualgemm<1><<<g1, 256, 0, stream>>>(agg, h1, c2Wrel + i * 128 * 128,
                                            c2Wroot + i * 128 * 128, c2brel + i * 128,
                                            h2, N, 128, 128, 128);

        // lin: e_i = h2 @ linW + linb   (128 -> 96)
        dim3 g2((N + 63) / 64, 2);
        dualgemm<0><<<g2, 256, 0, stream>>>(h2, h2, linW + i * 128 * 96,
                                            linW + i * 128 * 96, linb + i * 96,
                                            es[i], N, 128, 0, 96);
    }

    // interpolation: i1 = A1 @ e1, i2 = A2 @ e2 (scatter by rows)
    hipMemsetAsync(i1, 0, (size_t)N0 * 96 * sizeof(float), stream);
    hipMemsetAsync(i2, 0, (size_t)N0 * 96 * sizeof(float), stream);
    interp_scatter<<<((size_t)NNZ * 96 + 255) / 256, 256, 0, stream>>>(e1, A1r, A1c, A1v, i1, NNZ);
    interp_scatter<<<((size_t)NNZ * 96 + 255) / 256, 256, 0, stream>>>(e2, A2r, A2c, A2v, i2, NNZ);

    // decoder
    dim3 gd(1024, 3);
    decoder<<<gd, 256, 0, stream>>>(e0, i1, i2, dW0, db0, dWout, dbout, out, N0);
}

// Round 2
// 1114.864 us; speedup vs baseline: 2.5764x; 2.5764x over previous
//
#include <hip/hip_runtime.h>
#include <math.h>

#define N0 50000
#define N1 12500
#define N2 3125
#define NNZ 200000

// ================= CSR build =================

__global__ void count_k(const int* __restrict__ dst, int* __restrict__ cnt, int E) {
    int e = blockIdx.x * blockDim.x + threadIdx.x;
    if (e < E) atomicAdd(&cnt[dst[e]], 1);
}

// single-block exclusive scan, 1024 threads, wave-shfl based. offs[n] = total.
__global__ __launch_bounds__(1024) void scan_excl(const int* __restrict__ cnt,
                                                  int* __restrict__ offs, int n) {
    __shared__ int wsum[16];
    __shared__ int carry;
    int lane = threadIdx.x & 63;
    int wid = threadIdx.x >> 6;
    if (threadIdx.x == 0) carry = 0;
    __syncthreads();
    for (int c = 0; c < n; c += 1024) {
        int i = c + threadIdx.x;
        int v = (i < n) ? cnt[i] : 0;
        int s = v;
#pragma unroll
        for (int off = 1; off < 64; off <<= 1) {
            int t = __shfl_up(s, off, 64);
            if (lane >= off) s += t;
        }
        if (lane == 63) wsum[wid] = s;
        __syncthreads();
        if (wid == 0 && lane < 16) {
            int w = wsum[lane];
#pragma unroll
            for (int off = 1; off < 16; off <<= 1) {
                int t = __shfl_up(w, off, 64);
                if (lane >= off) w += t;
            }
            wsum[lane] = w;  // inclusive
        }
        __syncthreads();
        int waveoff = (wid == 0) ? 0 : wsum[wid - 1];
        if (i < n) offs[i] = carry + waveoff + s - v;
        int total = wsum[15];
        __syncthreads();
        if (threadIdx.x == 0) carry += total;
        __syncthreads();
    }
    if (threadIdx.x == 0) offs[n] = carry;
}

__global__ void fill_csr(const int* __restrict__ src, const int* __restrict__ dst,
                         const int* __restrict__ offs, int* __restrict__ cur,
                         int* __restrict__ csrc, int E) {
    int e = blockIdx.x * blockDim.x + threadIdx.x;
    if (e >= E) return;
    int d = dst[e];
    int p = atomicAdd(&cur[d], 1);
    csrc[offs[d] + p] = src[e];
}

__global__ void fill_csr_v(const int* __restrict__ rows, const int* __restrict__ cols,
                           const float* __restrict__ vals, const int* __restrict__ offs,
                           int* __restrict__ cur, int* __restrict__ ccol,
                           float* __restrict__ cval, int nnz) {
    int k = blockIdx.x * blockDim.x + threadIdx.x;
    if (k >= nnz) return;
    int r = rows[k];
    int p = atomicAdd(&cur[r], 1);
    int q = offs[r] + p;
    ccol[q] = cols[k];
    cval[q] = vals[k];
}

// ================= gathers (no atomics) =================

__global__ void gather6(const float* __restrict__ x, const int* __restrict__ offs,
                        const int* __restrict__ csrc, float* __restrict__ agg, int N) {
    int n = blockIdx.x * blockDim.x + threadIdx.x;
    if (n >= N) return;
    float a0 = 0, a1 = 0, a2 = 0, a3 = 0, a4 = 0, a5 = 0;
    int b = offs[n], e = offs[n + 1];
    for (int j = b; j < e; j++) {
        const float* p = x + (size_t)csrc[j] * 6;
        a0 += p[0]; a1 += p[1]; a2 += p[2]; a3 += p[3]; a4 += p[4]; a5 += p[5];
    }
    float* o = agg + (size_t)n * 6;
    o[0] = a0; o[1] = a1; o[2] = a2; o[3] = a3; o[4] = a4; o[5] = a5;
}

// 32 threads per node, each owns one float4 of the 128 features
__global__ __launch_bounds__(256) void gatherH(const float* __restrict__ h,
                                               const int* __restrict__ offs,
                                               const int* __restrict__ csrc,
                                               float* __restrict__ agg, int N) {
    int t = blockIdx.x * blockDim.x + threadIdx.x;
    int n = t >> 5;
    int g = t & 31;
    if (n >= N) return;
    float4 a = {0.f, 0.f, 0.f, 0.f};
    int b = offs[n], e = offs[n + 1];
    for (int j = b; j < e; j++) {
        int s = csrc[j];
        float4 v = ((const float4*)(h + (size_t)s * 128))[g];
        a.x += v.x; a.y += v.y; a.z += v.z; a.w += v.w;
    }
    ((float4*)(agg + (size_t)n * 128))[g] = a;
}

// 24 threads per node (96 features / float4)
__global__ __launch_bounds__(256) void interp_gather(const float* __restrict__ e,
                                                     const int* __restrict__ offs,
                                                     const int* __restrict__ ccol,
                                                     const float* __restrict__ cval,
                                                     float* __restrict__ outb, int N) {
    int t = blockIdx.x * blockDim.x + threadIdx.x;
    int n = t / 24;
    int g = t % 24;
    if (n >= N) return;
    float4 a = {0.f, 0.f, 0.f, 0.f};
    int b = offs[n], en = offs[n + 1];
    for (int j = b; j < en; j++) {
        int c = ccol[j];
        float v = cval[j];
        float4 w = ((const float4*)(e + (size_t)c * 96))[g];
        a.x += v * w.x; a.y += v * w.y; a.z += v * w.z; a.w += v * w.w;
    }
    ((float4*)(outb + (size_t)n * 96))[g] = a;
}

// ================= generic dual-input GEMM =================
// C[m,j] = act( A1[m,:]@W1 + A2[m,:]@W2 + bias[j] ); ACT: 0 none, 1 relu
template <int ACT>
__global__ __launch_bounds__(256) void dualgemm(
        const float* __restrict__ A1, const float* __restrict__ A2,
        const float* __restrict__ W1, const float* __restrict__ W2,
        const float* __restrict__ bias, float* __restrict__ C,
        int M, int K1, int K2, int J) {
    const int BM = 64, BN = 64, BK = 16;
    __shared__ float As[BK][BM + 1];
    __shared__ float Ws[BK][BN];
    int m0 = blockIdx.x * BM;
    int n0 = blockIdx.y * BN;
    int tid = threadIdx.x;
    int tm = tid >> 4, tn = tid & 15;
    int Ktot = K1 + K2;
    float acc[4][4] = {};
    for (int kt = 0; kt < Ktot; kt += BK) {
#pragma unroll
        for (int q = 0; q < 4; q++) {
            int idx = tid + q * 256;
            int row = idx >> 4;
            int kk = idx & 15;
            int m = m0 + row, k = kt + kk;
            float v = 0.f;
            if (m < M && k < Ktot)
                v = (k < K1) ? A1[(size_t)m * K1 + k] : A2[(size_t)m * K2 + (k - K1)];
            As[kk][row] = v;
        }
#pragma unroll
        for (int q = 0; q < 4; q++) {
            int idx = tid + q * 256;
            int kk = idx >> 6;
            int n = idx & 63;
            int k = kt + kk, nn = n0 + n;
            float v = 0.f;
            if (k < Ktot && nn < J)
                v = (k < K1) ? W1[(size_t)k * J + nn] : W2[(size_t)(k - K1) * J + nn];
            Ws[kk][n] = v;
        }
        __syncthreads();
#pragma unroll
        for (int k = 0; k < BK; k++) {
            float av[4], wv[4];
#pragma unroll
            for (int i = 0; i < 4; i++) av[i] = As[k][tm * 4 + i];
#pragma unroll
            for (int j = 0; j < 4; j++) wv[j] = Ws[k][tn * 4 + j];
#pragma unroll
            for (int i = 0; i < 4; i++)
#pragma unroll
                for (int j = 0; j < 4; j++) acc[i][j] += av[i] * wv[j];
        }
        __syncthreads();
    }
#pragma unroll
    for (int i = 0; i < 4; i++) {
        int m = m0 + tm * 4 + i;
        if (m >= M) continue;
#pragma unroll
        for (int j = 0; j < 4; j++) {
            int n = n0 + tn * 4 + j;
            if (n >= J) continue;
            float v = acc[i][j] + bias[n];
            if (ACT == 1) v = fmaxf(v, 0.f);
            C[(size_t)m * J + n] = v;
        }
    }
}

// ================= decoder =================
__global__ __launch_bounds__(256) void decoder(
        const float* __restrict__ e0, const float* __restrict__ i1,
        const float* __restrict__ i2, const float* __restrict__ W0,
        const float* __restrict__ b0, const float* __restrict__ Wout,
        const float* __restrict__ bout, float* __restrict__ out, int N) {
    int ch = blockIdx.y;
    __shared__ float sW[96 * 64];
    __shared__ float sWout[64];
    __shared__ float sb0[64];
    __shared__ float sbout;
    for (int q = threadIdx.x; q < 96 * 64; q += blockDim.x) sW[q] = W0[ch * 96 * 64 + q];
    if (threadIdx.x < 64) {
        sWout[threadIdx.x] = Wout[ch * 64 + threadIdx.x];
        sb0[threadIdx.x] = b0[ch * 64 + threadIdx.x];
    }
    if (threadIdx.x == 0) sbout = bout[ch];
    __syncthreads();
    int lane = threadIdx.x & 63;
    int wave = threadIdx.x >> 6;
    int wavesTotal = gridDim.x * (blockDim.x >> 6);
    for (int n = blockIdx.x * (blockDim.x >> 6) + wave; n < N; n += wavesTotal) {
        const float* pe0 = e0 + (size_t)n * 96 + ch * 32;
        const float* pi1 = i1 + (size_t)n * 96 + ch * 32;
        const float* pi2 = i2 + (size_t)n * 96 + ch * 32;
        float acc = sb0[lane];
#pragma unroll
        for (int f = 0; f < 32; f++) acc += pe0[f] * sW[f * 64 + lane];
#pragma unroll
        for (int f = 0; f < 32; f++) acc += pi1[f] * sW[(32 + f) * 64 + lane];
#pragma unroll
        for (int f = 0; f < 32; f++) acc += pi2[f] * sW[(64 + f) * 64 + lane];
        float h = acc > 0.f ? acc : (expf(acc) - 1.0f);
        float p = h * sWout[lane];
#pragma unroll
        for (int off = 32; off > 0; off >>= 1) p += __shfl_down(p, off, 64);
        if (lane == 0) out[(size_t)n * 3 + ch] = p + sbout;
    }
}

// ================= host launch =================

extern "C" void kernel_launch(void* const* d_in, const int* in_sizes, int n_in,
                              void* d_out, int out_size, void* d_ws, size_t ws_size,
                              hipStream_t stream) {
    const float* x0 = (const float*)d_in[0];
    const float* x1 = (const float*)d_in[1];
    const float* x2 = (const float*)d_in[2];
    const int* ei0 = (const int*)d_in[3];
    const int* ei1 = (const int*)d_in[4];
    const int* ei2 = (const int*)d_in[5];
    const int* A1r = (const int*)d_in[6];
    const int* A1c = (const int*)d_in[7];
    const float* A1v = (const float*)d_in[8];
    const int* A2r = (const int*)d_in[9];
    const int* A2c = (const int*)d_in[10];
    const float* A2v = (const float*)d_in[11];
    const float* c1Wrel = (const float*)d_in[12];
    const float* c1brel = (const float*)d_in[13];
    const float* c1Wroot = (const float*)d_in[14];
    const float* c2Wrel = (const float*)d_in[15];
    const float* c2brel = (const float*)d_in[16];
    const float* c2Wroot = (const float*)d_in[17];
    const float* linW = (const float*)d_in[18];
    const float* linb = (const float*)d_in[19];
    const float* dW0 = (const float*)d_in[20];
    const float* db0 = (const float*)d_in[21];
    const float* dWout = (const float*)d_in[22];
    const float* dbout = (const float*)d_in[23];
    float* out = (float*)d_out;

    // ---- workspace layout (float elements) ----
    float* ws = (float*)d_ws;
    float* h1 = ws;                   // 6.4M  (N0*128)
    float* agg = ws + 6400000;        // 6.4M
    float* h2 = ws + 12800000;        // 6.4M
    float* e0 = ws + 19200000;        // 4.8M  (N0*96)
    float* e1 = ws + 24000000;        // 1.2M
    float* e2 = ws + 25200000;        // 0.3M
    float* i1 = ws;                   // overlay h1 (valid after encoder phase)
    float* i2 = ws + 4800000;         // overlay h1/agg
    // int region for CSR
    int* ibase = (int*)(ws + 25500000);
    int* cnt = ibase;                 // 50001 (doubles as cursor)
    int* offs = ibase + 50001;        // 50001
    int* csrc = ibase + 100002;       // 800000 (also ccol for interp)
    float* cval = (float*)(ibase + 900002);  // 200000 (interp vals)
    // total ≈ 26.6M floats ≈ 106.4 MB

    const float* xs[3] = {x0, x1, x2};
    const int* eis[3] = {ei0, ei1, ei2};
    const int Ns[3] = {N0, N1, N2};
    const int Es[3] = {800000, 200000, 50000};
    float* es[3] = {e0, e1, e2};

    for (int i = 0; i < 3; i++) {
        int N = Ns[i], E = Es[i];
        const float* x = xs[i];
        const int* src = eis[i];
        const int* dst = eis[i] + E;

        // CSR build (by dst) — used by both convs
        hipMemsetAsync(cnt, 0, (size_t)N * sizeof(int), stream);
        count_k<<<(E + 255) / 256, 256, 0, stream>>>(dst, cnt, E);
        scan_excl<<<1, 1024, 0, stream>>>(cnt, offs, N);
        hipMemsetAsync(cnt, 0, (size_t)N * sizeof(int), stream);
        fill_csr<<<(E + 255) / 256, 256, 0, stream>>>(src, dst, offs, cnt, csrc, E);

        // conv1
        gather6<<<(N + 255) / 256, 256, 0, stream>>>(x, offs, csrc, agg, N);
        dim3 g1((N + 63) / 64, 2);
        dualgemm<1><<<g1, 256, 0, stream>>>(agg, x, c1Wrel + i * 6 * 128,
                                            c1Wroot + i * 6 * 128, c1brel + i * 128,
                                            h1, N, 6, 6, 128);

        // conv2
        gatherH<<<((size_t)N * 32 + 255) / 256, 256, 0, stream>>>(h1, offs, csrc, agg, N);
        dualgemm<1><<<g1, 256, 0, stream>>>(agg, h1, c2Wrel + i * 128 * 128,
                                            c2Wroot + i * 128 * 128, c2brel + i * 128,
                                            h2, N, 128, 128, 128);

        // lin: 128 -> 96
        dim3 g2((N + 63) / 64, 2);
        dualgemm<0><<<g2, 256, 0, stream>>>(h2, h2, linW + i * 128 * 96,
                                            linW + i * 128 * 96, linb + i * 96,
                                            es[i], N, 128, 0, 96);
    }

    // ---- interpolation via CSR gather ----
    const int* Ars[2] = {A1r, A2r};
    const int* Acs[2] = {A1c, A2c};
    const float* Avs[2] = {A1v, A2v};
    const float* Aes[2] = {e1, e2};
    float* Ais[2] = {i1, i2};
    for (int a = 0; a < 2; a++) {
        hipMemsetAsync(cnt, 0, (size_t)N0 * sizeof(int), stream);
        count_k<<<(NNZ + 255) / 256, 256, 0, stream>>>(Ars[a], cnt, NNZ);
        scan_excl<<<1, 1024, 0, stream>>>(cnt, offs, N0);
        hipMemsetAsync(cnt, 0, (size_t)N0 * sizeof(int), stream);
        fill_csr_v<<<(NNZ + 255) / 256, 256, 0, stream>>>(Ars[a], Acs[a], Avs[a], offs,
                                                          cnt, csrc, cval, NNZ);
        interp_gather<<<((size_t)N0 * 24 + 255) / 256, 256, 0, stream>>>(
            Aes[a], offs, csrc, cval, Ais[a], N0);
    }

    // ---- decoder ----
    dim3 gd(1024, 3);
    decoder<<<gd, 256, 0, stream>>>(e0, i1, i2, dW0, db0, dWout, dbout, out, N0);
}

// Round 3
// 1030.936 us; speedup vs baseline: 2.7861x; 1.0814x over previous
//
#include <hip/hip_runtime.h>
#include <math.h>

#define N0 50000
#define N1 12500
#define N2 3125
#define NNZ 200000

// ================= CSR build =================

__global__ void count_k(const int* __restrict__ dst, int* __restrict__ cnt, int E) {
    int e = blockIdx.x * blockDim.x + threadIdx.x;
    if (e < E) atomicAdd(&cnt[dst[e]], 1);
}

// single-block exclusive scan, 1024 threads, 8 elems/thread.
// Also ZEROES cnt behind itself (so next count_k needs no memset).
// offs[i] = exclusive prefix; offs[n] = total.
__global__ __launch_bounds__(1024) void scan_excl(int* __restrict__ cnt,
                                                  int* __restrict__ offs, int n) {
    __shared__ int wsum[16];
    __shared__ int carry_s;
    int lane = threadIdx.x & 63;
    int wid = threadIdx.x >> 6;
    if (threadIdx.x == 0) carry_s = 0;
    __syncthreads();
    for (int c = 0; c < n; c += 8192) {
        int base = c + threadIdx.x * 8;
        int v[8];
        int tsum = 0;
#pragma unroll
        for (int q = 0; q < 8; q++) {
            int i = base + q;
            v[q] = (i < n) ? cnt[i] : 0;
            if (i < n) cnt[i] = 0;
            tsum += v[q];
        }
        int s = tsum;
#pragma unroll
        for (int off = 1; off < 64; off <<= 1) {
            int t = __shfl_up(s, off, 64);
            if (lane >= off) s += t;
        }
        if (lane == 63) wsum[wid] = s;
        __syncthreads();
        if (wid == 0 && lane < 16) {
            int w = wsum[lane];
#pragma unroll
            for (int off = 1; off < 16; off <<= 1) {
                int t = __shfl_up(w, off, 64);
                if (lane >= off) w += t;
            }
            wsum[lane] = w;  // inclusive wave sums
        }
        __syncthreads();
        int waveoff = (wid == 0) ? 0 : wsum[wid - 1];
        int total = wsum[15];
        int run = carry_s + waveoff + (s - tsum);
#pragma unroll
        for (int q = 0; q < 8; q++) {
            int i = base + q;
            if (i < n) offs[i] = run;
            run += v[q];
        }
        __syncthreads();
        if (threadIdx.x == 0) carry_s += total;
        __syncthreads();
    }
    if (threadIdx.x == 0) offs[n] = carry_s;
}

// fill uses offs itself as cursor: after this kernel offs[d] = END of segment d
// (start of segment d = offs[d-1], or 0 for d==0).
__global__ void fill_csr(const int* __restrict__ src, const int* __restrict__ dst,
                         int* __restrict__ offs, int* __restrict__ csrc, int E) {
    int e = blockIdx.x * blockDim.x + threadIdx.x;
    if (e >= E) return;
    int d = dst[e];
    int p = atomicAdd(&offs[d], 1);
    csrc[p] = src[e];
}

__global__ void fill_csr_v(const int* __restrict__ rows, const int* __restrict__ cols,
                           const float* __restrict__ vals, int* __restrict__ offs,
                           int* __restrict__ ccol, float* __restrict__ cval, int nnz) {
    int k = blockIdx.x * blockDim.x + threadIdx.x;
    if (k >= nnz) return;
    int r = rows[k];
    int p = atomicAdd(&offs[r], 1);
    ccol[p] = cols[k];
    cval[p] = vals[k];
}

// ================= gathers (no atomics) =================
// Convention: segment n spans [ (n? offs[n-1] : 0), offs[n] ).

__global__ void gather6(const float* __restrict__ x, const int* __restrict__ offs,
                        const int* __restrict__ csrc, float* __restrict__ agg, int N) {
    int n = blockIdx.x * blockDim.x + threadIdx.x;
    if (n >= N) return;
    float a0 = 0, a1 = 0, a2 = 0, a3 = 0, a4 = 0, a5 = 0;
    int b = n ? offs[n - 1] : 0;
    int e = offs[n];
    for (int j = b; j < e; j++) {
        const float* p = x + (size_t)csrc[j] * 6;
        a0 += p[0]; a1 += p[1]; a2 += p[2]; a3 += p[3]; a4 += p[4]; a5 += p[5];
    }
    float* o = agg + (size_t)n * 6;
    o[0] = a0; o[1] = a1; o[2] = a2; o[3] = a3; o[4] = a4; o[5] = a5;
}

// 32 threads per node, each owns one float4 of the 128 features
__global__ __launch_bounds__(256) void gatherH(const float* __restrict__ h,
                                               const int* __restrict__ offs,
                                               const int* __restrict__ csrc,
                                               float* __restrict__ agg, int N) {
    int t = blockIdx.x * blockDim.x + threadIdx.x;
    int n = t >> 5;
    int g = t & 31;
    if (n >= N) return;
    float4 a = {0.f, 0.f, 0.f, 0.f};
    int b = n ? offs[n - 1] : 0;
    int e = offs[n];
    for (int j = b; j < e; j++) {
        int s = csrc[j];
        float4 v = ((const float4*)(h + (size_t)s * 128))[g];
        a.x += v.x; a.y += v.y; a.z += v.z; a.w += v.w;
    }
    ((float4*)(agg + (size_t)n * 128))[g] = a;
}

// 24 threads per node (96 features / float4)
__global__ __launch_bounds__(256) void interp_gather(const float* __restrict__ e,
                                                     const int* __restrict__ offs,
                                                     const int* __restrict__ ccol,
                                                     const float* __restrict__ cval,
                                                     float* __restrict__ outb, int N) {
    int t = blockIdx.x * blockDim.x + threadIdx.x;
    int n = t / 24;
    int g = t % 24;
    if (n >= N) return;
    float4 a = {0.f, 0.f, 0.f, 0.f};
    int b = n ? offs[n - 1] : 0;
    int en = offs[n];
    for (int j = b; j < en; j++) {
        int c = ccol[j];
        float v = cval[j];
        float4 w = ((const float4*)(e + (size_t)c * 96))[g];
        a.x += v * w.x; a.y += v * w.y; a.z += v * w.z; a.w += v * w.w;
    }
    ((float4*)(outb + (size_t)n * 96))[g] = a;
}

// ================= generic dual-input GEMM =================
template <int ACT>
__global__ __launch_bounds__(256) void dualgemm(
        const float* __restrict__ A1, const float* __restrict__ A2,
        const float* __restrict__ W1, const float* __restrict__ W2,
        const float* __restrict__ bias, float* __restrict__ C,
        int M, int K1, int K2, int J) {
    const int BM = 64, BN = 64, BK = 16;
    __shared__ float As[BK][BM + 1];
    __shared__ float Ws[BK][BN];
    int m0 = blockIdx.x * BM;
    int n0 = blockIdx.y * BN;
    int tid = threadIdx.x;
    int tm = tid >> 4, tn = tid & 15;
    int Ktot = K1 + K2;
    float acc[4][4] = {};
    for (int kt = 0; kt < Ktot; kt += BK) {
#pragma unroll
        for (int q = 0; q < 4; q++) {
            int idx = tid + q * 256;
            int row = idx >> 4;
            int kk = idx & 15;
            int m = m0 + row, k = kt + kk;
            float v = 0.f;
            if (m < M && k < Ktot)
                v = (k < K1) ? A1[(size_t)m * K1 + k] : A2[(size_t)m * K2 + (k - K1)];
            As[kk][row] = v;
        }
#pragma unroll
        for (int q = 0; q < 4; q++) {
            int idx = tid + q * 256;
            int kk = idx >> 6;
            int n = idx & 63;
            int k = kt + kk, nn = n0 + n;
            float v = 0.f;
            if (k < Ktot && nn < J)
                v = (k < K1) ? W1[(size_t)k * J + nn] : W2[(size_t)(k - K1) * J + nn];
            Ws[kk][n] = v;
        }
        __syncthreads();
#pragma unroll
        for (int k = 0; k < BK; k++) {
            float av[4], wv[4];
#pragma unroll
            for (int i = 0; i < 4; i++) av[i] = As[k][tm * 4 + i];
#pragma unroll
            for (int j = 0; j < 4; j++) wv[j] = Ws[k][tn * 4 + j];
#pragma unroll
            for (int i = 0; i < 4; i++)
#pragma unroll
                for (int j = 0; j < 4; j++) acc[i][j] += av[i] * wv[j];
        }
        __syncthreads();
    }
#pragma unroll
    for (int i = 0; i < 4; i++) {
        int m = m0 + tm * 4 + i;
        if (m >= M) continue;
#pragma unroll
        for (int j = 0; j < 4; j++) {
            int n = n0 + tn * 4 + j;
            if (n >= J) continue;
            float v = acc[i][j] + bias[n];
            if (ACT == 1) v = fmaxf(v, 0.f);
            C[(size_t)m * J + n] = v;
        }
    }
}

// ================= fused decoder (tile GEMM + ELU + Wout reduction) ========
// Block: 64 nodes x 64 hidden, K=96 in one shot. grid=(ceil(N/64), 3 channels).
__global__ __launch_bounds__(256) void decoder_fused(
        const float* __restrict__ e0, const float* __restrict__ i1,
        const float* __restrict__ i2, const float* __restrict__ W0,
        const float* __restrict__ b0, const float* __restrict__ Wout,
        const float* __restrict__ bout, float* __restrict__ out, int N) {
    int ch = blockIdx.y;
    __shared__ float As[96][68];     // [k][node], pad 68 (17*16B rows, b128-aligned)
    __shared__ float Ws[96 * 64];    // [k][hidden]
    __shared__ float sb0[64];
    __shared__ float sWo[64];
    __shared__ float red[64][17];
    int tid = threadIdx.x;
    int m0 = blockIdx.x * 64;

    for (int idx = tid; idx < 96 * 64; idx += 256) Ws[idx] = W0[ch * 96 * 64 + idx];
    if (tid < 64) {
        sb0[tid] = b0[ch * 64 + tid];
        sWo[tid] = Wout[ch * 64 + tid];
    }
    for (int idx = tid; idx < 64 * 96; idx += 256) {
        int row = idx / 96;
        int k = idx % 96;
        int m = m0 + row;
        float v = 0.f;
        if (m < N) {
            const float* base = (k < 32) ? e0 : (k < 64 ? i1 : i2);
            v = base[(size_t)m * 96 + ch * 32 + (k & 31)];
        }
        As[k][row] = v;
    }
    __syncthreads();

    int tm = tid >> 4, tn = tid & 15;
    float acc[4][4] = {};
#pragma unroll
    for (int k = 0; k < 96; k++) {
        float4 a4 = *(const float4*)(&As[k][tm * 4]);
        float4 w4 = *(const float4*)(&Ws[k * 64 + tn * 4]);
        acc[0][0] += a4.x * w4.x; acc[0][1] += a4.x * w4.y; acc[0][2] += a4.x * w4.z; acc[0][3] += a4.x * w4.w;
        acc[1][0] += a4.y * w4.x; acc[1][1] += a4.y * w4.y; acc[1][2] += a4.y * w4.z; acc[1][3] += a4.y * w4.w;
        acc[2][0] += a4.z * w4.x; acc[2][1] += a4.z * w4.y; acc[2][2] += a4.z * w4.z; acc[2][3] += a4.z * w4.w;
        acc[3][0] += a4.w * w4.x; acc[3][1] += a4.w * w4.y; acc[3][2] += a4.w * w4.z; acc[3][3] += a4.w * w4.w;
    }
    // bias + ELU + dot with Wout (partial over this thread's 4 hidden units)
    float part[4];
#pragma unroll
    for (int i = 0; i < 4; i++) {
        float p = 0.f;
#pragma unroll
        for (int j = 0; j < 4; j++) {
            float h = acc[i][j] + sb0[tn * 4 + j];
            h = h > 0.f ? h : (expf(h) - 1.0f);
            p += h * sWo[tn * 4 + j];
        }
        part[i] = p;
    }
#pragma unroll
    for (int i = 0; i < 4; i++) red[tm * 4 + i][tn] = part[i];
    __syncthreads();
    if (tid < 64) {
        float s = 0.f;
#pragma unroll
        for (int t = 0; t < 16; t++) s += red[tid][t];
        int m = m0 + tid;
        if (m < N) out[(size_t)m * 3 + ch] = s + bout[ch];
    }
}

// ================= host launch =================

extern "C" void kernel_launch(void* const* d_in, const int* in_sizes, int n_in,
                              void* d_out, int out_size, void* d_ws, size_t ws_size,
                              hipStream_t stream) {
    const float* x0 = (const float*)d_in[0];
    const float* x1 = (const float*)d_in[1];
    const float* x2 = (const float*)d_in[2];
    const int* ei0 = (const int*)d_in[3];
    const int* ei1 = (const int*)d_in[4];
    const int* ei2 = (const int*)d_in[5];
    const int* A1r = (const int*)d_in[6];
    const int* A1c = (const int*)d_in[7];
    const float* A1v = (const float*)d_in[8];
    const int* A2r = (const int*)d_in[9];
    const int* A2c = (const int*)d_in[10];
    const float* A2v = (const float*)d_in[11];
    const float* c1Wrel = (const float*)d_in[12];
    const float* c1brel = (const float*)d_in[13];
    const float* c1Wroot = (const float*)d_in[14];
    const float* c2Wrel = (const float*)d_in[15];
    const float* c2brel = (const float*)d_in[16];
    const float* c2Wroot = (const float*)d_in[17];
    const float* linW = (const float*)d_in[18];
    const float* linb = (const float*)d_in[19];
    const float* dW0 = (const float*)d_in[20];
    const float* db0 = (const float*)d_in[21];
    const float* dWout = (const float*)d_in[22];
    const float* dbout = (const float*)d_in[23];
    float* out = (float*)d_out;

    // ---- workspace layout (float elements) ----
    float* ws = (float*)d_ws;
    float* h1 = ws;                   // 6.4M  (N0*128)
    float* agg = ws + 6400000;        // 6.4M
    float* h2 = ws + 12800000;        // 6.4M
    float* e0 = ws + 19200000;        // 4.8M  (N0*96)
    float* e1 = ws + 24000000;        // 1.2M
    float* e2 = ws + 25200000;        // 0.3M
    float* i1 = ws;                   // overlay h1 (valid after encoder phase)
    float* i2 = ws + 4800000;         // overlay h1/agg
    int* ibase = (int*)(ws + 25500000);
    int* cnt = ibase;                 // 50001
    int* offs = ibase + 50001;        // 50001
    int* csrc = ibase + 100002;       // 800000 (also ccol for interp)
    float* cval = (float*)(ibase + 900002);  // 200000

    const float* xs[3] = {x0, x1, x2};
    const int* eis[3] = {ei0, ei1, ei2};
    const int Ns[3] = {N0, N1, N2};
    const int Es[3] = {800000, 200000, 50000};
    float* es[3] = {e0, e1, e2};

    // one memset for cnt at start; thereafter scan_excl zeroes it behind itself
    hipMemsetAsync(cnt, 0, (size_t)N0 * sizeof(int), stream);

    for (int i = 0; i < 3; i++) {
        int N = Ns[i], E = Es[i];
        const float* x = xs[i];
        const int* src = eis[i];
        const int* dst = eis[i] + E;

        // CSR build by dst (offs becomes inclusive ends after fill)
        count_k<<<(E + 255) / 256, 256, 0, stream>>>(dst, cnt, E);
        scan_excl<<<1, 1024, 0, stream>>>(cnt, offs, N);
        fill_csr<<<(E + 255) / 256, 256, 0, stream>>>(src, dst, offs, csrc, E);

        // conv1
        gather6<<<(N + 255) / 256, 256, 0, stream>>>(x, offs, csrc, agg, N);
        dim3 g1((N + 63) / 64, 2);
        dualgemm<1><<<g1, 256, 0, stream>>>(agg, x, c1Wrel + i * 6 * 128,
                                            c1Wroot + i * 6 * 128, c1brel + i * 128,
                                            h1, N, 6, 6, 128);

        // conv2
        gatherH<<<((size_t)N * 32 + 255) / 256, 256, 0, stream>>>(h1, offs, csrc, agg, N);
        dualgemm<1><<<g1, 256, 0, stream>>>(agg, h1, c2Wrel + i * 128 * 128,
                                            c2Wroot + i * 128 * 128, c2brel + i * 128,
                                            h2, N, 128, 128, 128);

        // lin: 128 -> 96
        dim3 g2((N + 63) / 64, 2);
        dualgemm<0><<<g2, 256, 0, stream>>>(h2, h2, linW + i * 128 * 96,
                                            linW + i * 128 * 96, linb + i * 96,
                                            es[i], N, 128, 0, 96);
    }

    // ---- interpolation via CSR gather ----
    const int* Ars[2] = {A1r, A2r};
    const int* Acs[2] = {A1c, A2c};
    const float* Avs[2] = {A1v, A2v};
    const float* Aes[2] = {e1, e2};
    float* Ais[2] = {i1, i2};
    for (int a = 0; a < 2; a++) {
        count_k<<<(NNZ + 255) / 256, 256, 0, stream>>>(Ars[a], cnt, NNZ);
        scan_excl<<<1, 1024, 0, stream>>>(cnt, offs, N0);
        fill_csr_v<<<(NNZ + 255) / 256, 256, 0, stream>>>(Ars[a], Acs[a], Avs[a], offs,
                                                          csrc, cval, NNZ);
        interp_gather<<<((size_t)N0 * 24 + 255) / 256, 256, 0, stream>>>(
            Aes[a], offs, csrc, cval, Ais[a], N0);
    }

    // ---- fused decoder ----
    dim3 gd((N0 + 63) / 64, 3);
    decoder_fused<<<gd, 256, 0, stream>>>(e0, i1, i2, dW0, db0, dWout, dbout, out, N0);
}

// Round 4
// 692.234 us; speedup vs baseline: 4.1494x; 1.4893x over previous
//
#include <hip/hip_runtime.h>
#include <math.h>

#define N0 50000
#define N1 12500
#define N2 3125
#define NNZ 200000

typedef __attribute__((ext_vector_type(8))) short short8;
typedef __attribute__((ext_vector_type(8))) unsigned short ushort8;
typedef __attribute__((ext_vector_type(4))) float floatx4;

// ================= CSR build =================

__global__ void count_k(const int* __restrict__ dst, int* __restrict__ cnt, int E) {
    int e = blockIdx.x * blockDim.x + threadIdx.x;
    if (e < E) atomicAdd(&cnt[dst[e]], 1);
}

// ---- 3-phase parallel exclusive scan (also zeroes cnt in phase C) ----
// chunk = 2048 elems per block (256 thr x 8)

__global__ __launch_bounds__(256) void scan_partial(const int* __restrict__ cnt,
                                                    int* __restrict__ bsum, int n) {
    __shared__ int wsum[4];
    int base = blockIdx.x * 2048 + threadIdx.x * 8;
    int s = 0;
#pragma unroll
    for (int q = 0; q < 8; q++) {
        int i = base + q;
        if (i < n) s += cnt[i];
    }
#pragma unroll
    for (int off = 32; off > 0; off >>= 1) s += __shfl_down(s, off, 64);
    int lane = threadIdx.x & 63, wid = threadIdx.x >> 6;
    if (lane == 0) wsum[wid] = s;
    __syncthreads();
    if (threadIdx.x == 0) bsum[blockIdx.x] = wsum[0] + wsum[1] + wsum[2] + wsum[3];
}

// single wave; G <= 64 guaranteed (n <= 50000 -> G <= 25)
__global__ void scan_blocksums(const int* __restrict__ bsum, int* __restrict__ bexcl,
                               int* __restrict__ total_out, int G) {
    int lane = threadIdx.x;
    int v = (lane < G) ? bsum[lane] : 0;
    int s = v;
#pragma unroll
    for (int off = 1; off < 64; off <<= 1) {
        int t = __shfl_up(s, off, 64);
        if (lane >= off) s += t;
    }
    if (lane < G) bexcl[lane] = s - v;
    if (lane == 63) *total_out = s;
}

__global__ __launch_bounds__(256) void scan_final(int* __restrict__ cnt,
                                                  int* __restrict__ offs,
                                                  const int* __restrict__ bexcl, int n) {
    __shared__ int wsum[4];
    int base = blockIdx.x * 2048 + threadIdx.x * 8;
    int lane = threadIdx.x & 63, wid = threadIdx.x >> 6;
    int v[8];
    int ts = 0;
#pragma unroll
    for (int q = 0; q < 8; q++) {
        int i = base + q;
        v[q] = (i < n) ? cnt[i] : 0;
        if (i < n) cnt[i] = 0;
        ts += v[q];
    }
    int s = ts;
#pragma unroll
    for (int off = 1; off < 64; off <<= 1) {
        int t = __shfl_up(s, off, 64);
        if (lane >= off) s += t;
    }
    if (lane == 63) wsum[wid] = s;
    __syncthreads();
    int woff = 0;
    for (int w = 0; w < wid; w++) woff += wsum[w];
    int run = bexcl[blockIdx.x] + woff + (s - ts);
#pragma unroll
    for (int q = 0; q < 8; q++) {
        int i = base + q;
        if (i < n) offs[i] = run;
        run += v[q];
    }
}

// fill uses offs itself as cursor: after fill, offs[d] = end of segment d.
__global__ void fill_csr(const int* __restrict__ src, const int* __restrict__ dst,
                         int* __restrict__ offs, int* __restrict__ csrc, int E) {
    int e = blockIdx.x * blockDim.x + threadIdx.x;
    if (e >= E) return;
    int d = dst[e];
    int p = atomicAdd(&offs[d], 1);
    csrc[p] = src[e];
}

__global__ void fill_csr_v(const int* __restrict__ rows, const int* __restrict__ cols,
                           const float* __restrict__ vals, int* __restrict__ offs,
                           int* __restrict__ ccol, float* __restrict__ cval, int nnz) {
    int k = blockIdx.x * blockDim.x + threadIdx.x;
    if (k >= nnz) return;
    int r = rows[k];
    int p = atomicAdd(&offs[r], 1);
    ccol[p] = cols[k];
    cval[p] = vals[k];
}

// ================= gathers =================
// segment n spans [ (n? offs[n-1] : 0), offs[n] )

__global__ void gather6(const float* __restrict__ x, const int* __restrict__ offs,
                        const int* __restrict__ csrc, float* __restrict__ agg, int N) {
    int n = blockIdx.x * blockDim.x + threadIdx.x;
    if (n >= N) return;
    float a0 = 0, a1 = 0, a2 = 0, a3 = 0, a4 = 0, a5 = 0;
    int b = n ? offs[n - 1] : 0;
    int e = offs[n];
    for (int j = b; j < e; j++) {
        const float* p = x + (size_t)csrc[j] * 6;
        a0 += p[0]; a1 += p[1]; a2 += p[2]; a3 += p[3]; a4 += p[4]; a5 += p[5];
    }
    float* o = agg + (size_t)n * 6;
    o[0] = a0; o[1] = a1; o[2] = a2; o[3] = a3; o[4] = a4; o[5] = a5;
}

__global__ __launch_bounds__(256) void gatherH(const float* __restrict__ h,
                                               const int* __restrict__ offs,
                                               const int* __restrict__ csrc,
                                               float* __restrict__ agg, int N) {
    int t = blockIdx.x * blockDim.x + threadIdx.x;
    int n = t >> 5;
    int g = t & 31;
    if (n >= N) return;
    float4 a = {0.f, 0.f, 0.f, 0.f};
    int b = n ? offs[n - 1] : 0;
    int e = offs[n];
    for (int j = b; j < e; j++) {
        int s = csrc[j];
        float4 v = ((const float4*)(h + (size_t)s * 128))[g];
        a.x += v.x; a.y += v.y; a.z += v.z; a.w += v.w;
    }
    ((float4*)(agg + (size_t)n * 128))[g] = a;
}

__global__ __launch_bounds__(256) void interp_gather(const float* __restrict__ e,
                                                     const int* __restrict__ offs,
                                                     const int* __restrict__ ccol,
                                                     const float* __restrict__ cval,
                                                     float* __restrict__ outb, int N) {
    int t = blockIdx.x * blockDim.x + threadIdx.x;
    int n = t / 24;
    int g = t % 24;
    if (n >= N) return;
    float4 a = {0.f, 0.f, 0.f, 0.f};
    int b = n ? offs[n - 1] : 0;
    int en = offs[n];
    for (int j = b; j < en; j++) {
        int c = ccol[j];
        float v = cval[j];
        float4 w = ((const float4*)(e + (size_t)c * 96))[g];
        a.x += v * w.x; a.y += v * w.y; a.z += v * w.z; a.w += v * w.w;
    }
    ((float4*)(outb + (size_t)n * 96))[g] = a;
}

// ================= split-bf16 helpers =================

__device__ inline void split_bf16(float x, unsigned short& hi, unsigned short& lo) {
    unsigned xb = __float_as_uint(x);
    hi = (unsigned short)(xb >> 16);
    float hf = __uint_as_float((unsigned)hi << 16);
    float rem = x - hf;
    lo = (unsigned short)(__float_as_uint(rem) >> 16);
}

// preconvert weights to transposed [n][k] hi/lo bf16 planes.
// conv2 (3 levels): Wt[n][k], K=256 (k<128: Wrel, else Wroot), 32768 elems/level
// lin   (3 levels): Wt[n][k], K=128, 12288 elems/level
__global__ void conv_weights(const float* __restrict__ c2Wrel, const float* __restrict__ c2Wroot,
                             const float* __restrict__ linW,
                             unsigned short* __restrict__ c2hi, unsigned short* __restrict__ c2lo,
                             unsigned short* __restrict__ lhi, unsigned short* __restrict__ llo) {
    int t = blockIdx.x * blockDim.x + threadIdx.x;
    if (t < 98304) {
        int i = t / 32768, r = t % 32768;
        int n = r / 256, k = r % 256;
        float w = (k < 128) ? c2Wrel[i * 16384 + k * 128 + n]
                            : c2Wroot[i * 16384 + (k - 128) * 128 + n];
        unsigned short hi, lo;
        split_bf16(w, hi, lo);
        c2hi[t] = hi; c2lo[t] = lo;
    } else if (t < 135168) {
        int u = t - 98304;
        int i = u / 12288, r = u % 12288;
        int n = r / 128, k = r % 128;
        float w = linW[i * 12288 + k * 96 + n];
        unsigned short hi, lo;
        split_bf16(w, hi, lo);
        lhi[u] = hi; llo[u] = lo;
    }
}

// ================= split-bf16 MFMA dual GEMM =================
// C[m,j] = act( [A1|A2][m,:] @ W + bias[j] ), W given as transposed hi/lo bf16
// planes Wt[n][Ktot]. Requires K1 % 32 == 0 (or K2 == 0), Ktot % 32 == 0, J <= 128.
// Block: 64 rows x 128 cols, 4 waves (each 32x64), BK=32.
template <int ACT>
__global__ __launch_bounds__(256) void mfma_dualgemm(
        const float* __restrict__ A1, const float* __restrict__ A2,
        const unsigned short* __restrict__ Wt_hi, const unsigned short* __restrict__ Wt_lo,
        const float* __restrict__ bias, float* __restrict__ C,
        int M, int K1, int K2, int J) {
    const int LDA = 40;  // LDS pitch (ushorts): 32 + 8 pad, keeps 16B alignment
    __shared__ unsigned short Ah[64 * LDA], Al[64 * LDA];
    __shared__ unsigned short Bh[128 * LDA], Bl[128 * LDA];
    int tid = threadIdx.x;
    int m0 = blockIdx.x * 64;
    int Ktot = K1 + K2;
    int lane = tid & 63, wid = tid >> 6;
    int waveM = wid & 1, waveN = wid >> 1;
    int l15 = lane & 15, quad = lane >> 4;

    floatx4 acc[2][4];
#pragma unroll
    for (int i = 0; i < 2; i++)
#pragma unroll
        for (int j = 0; j < 4; j++) acc[i][j] = (floatx4){0.f, 0.f, 0.f, 0.f};

    int arow = tid >> 2;       // 0..63
    int acol = (tid & 3) * 8;  // 0,8,16,24
    int brow = tid >> 1;       // 0..127
    int bcol = (tid & 1) * 16; // 0,16

    for (int kt = 0; kt < Ktot; kt += 32) {
        __syncthreads();
        // ---- stage A: fp32 -> hi/lo bf16 ----
        {
            float x[8];
            int m = m0 + arow;
            if (m < M) {
                int kg = kt + acol;
                const float* src;
                int kk;
                if (kg < K1) { src = A1 + (size_t)m * K1; kk = kg; }
                else { src = A2 + (size_t)m * K2; kk = kg - K1; }
                float4 u0 = *(const float4*)(src + kk);
                float4 u1 = *(const float4*)(src + kk + 4);
                x[0] = u0.x; x[1] = u0.y; x[2] = u0.z; x[3] = u0.w;
                x[4] = u1.x; x[5] = u1.y; x[6] = u1.z; x[7] = u1.w;
            } else {
#pragma unroll
                for (int q = 0; q < 8; q++) x[q] = 0.f;
            }
            ushort8 hv, lv;
#pragma unroll
            for (int q = 0; q < 8; q++) {
                unsigned short h, l;
                split_bf16(x[q], h, l);
                hv[q] = h; lv[q] = l;
            }
            *(ushort8*)(&Ah[arow * LDA + acol]) = hv;
            *(ushort8*)(&Al[arow * LDA + acol]) = lv;
        }
        // ---- stage B: copy preconverted transposed weights ----
        {
            ushort8 h0, h1, l0, l1;
            if (brow < J) {
                const unsigned short* ph = Wt_hi + (size_t)brow * Ktot + kt + bcol;
                const unsigned short* pl = Wt_lo + (size_t)brow * Ktot + kt + bcol;
                h0 = *(const ushort8*)ph; h1 = *(const ushort8*)(ph + 8);
                l0 = *(const ushort8*)pl; l1 = *(const ushort8*)(pl + 8);
            } else {
                h0 = (ushort8)0; h1 = (ushort8)0; l0 = (ushort8)0; l1 = (ushort8)0;
            }
            *(ushort8*)(&Bh[brow * LDA + bcol]) = h0;
            *(ushort8*)(&Bh[brow * LDA + bcol + 8]) = h1;
            *(ushort8*)(&Bl[brow * LDA + bcol]) = l0;
            *(ushort8*)(&Bl[brow * LDA + bcol + 8]) = l1;
        }
        __syncthreads();
        // ---- MFMA ----
        short8 af[2][2];
#pragma unroll
        for (int mt = 0; mt < 2; mt++) {
            int r = waveM * 32 + mt * 16 + l15;
            af[mt][0] = *(const short8*)(&Ah[r * LDA + quad * 8]);
            af[mt][1] = *(const short8*)(&Al[r * LDA + quad * 8]);
        }
#pragma unroll
        for (int nt = 0; nt < 4; nt++) {
            int c = waveN * 64 + nt * 16 + l15;
            short8 bh = *(const short8*)(&Bh[c * LDA + quad * 8]);
            short8 bl = *(const short8*)(&Bl[c * LDA + quad * 8]);
#pragma unroll
            for (int mt = 0; mt < 2; mt++) {
                acc[mt][nt] = __builtin_amdgcn_mfma_f32_16x16x32_bf16(af[mt][0], bh, acc[mt][nt], 0, 0, 0);
                acc[mt][nt] = __builtin_amdgcn_mfma_f32_16x16x32_bf16(af[mt][0], bl, acc[mt][nt], 0, 0, 0);
                acc[mt][nt] = __builtin_amdgcn_mfma_f32_16x16x32_bf16(af[mt][1], bh, acc[mt][nt], 0, 0, 0);
            }
        }
    }
    // ---- epilogue ----
    float bs[4];
#pragma unroll
    for (int nt = 0; nt < 4; nt++) {
        int c = waveN * 64 + nt * 16 + l15;
        bs[nt] = (c < J) ? bias[c] : 0.f;
    }
#pragma unroll
    for (int mt = 0; mt < 2; mt++) {
#pragma unroll
        for (int r = 0; r < 4; r++) {
            int grow = m0 + waveM * 32 + mt * 16 + quad * 4 + r;
            if (grow >= M) continue;
#pragma unroll
            for (int nt = 0; nt < 4; nt++) {
                int c = waveN * 64 + nt * 16 + l15;
                if (c >= J) continue;
                float v = acc[mt][nt][r] + bs[nt];
                if (ACT == 1) v = fmaxf(v, 0.f);
                C[(size_t)grow * J + c] = v;
            }
        }
    }
}

// ================= fp32 dual GEMM (conv1 only, K=12) =================
template <int ACT>
__global__ __launch_bounds__(256) void dualgemm(
        const float* __restrict__ A1, const float* __restrict__ A2,
        const float* __restrict__ W1, const float* __restrict__ W2,
        const float* __restrict__ bias, float* __restrict__ C,
        int M, int K1, int K2, int J) {
    const int BM = 64, BN = 64, BK = 16;
    __shared__ float As[BK][BM + 1];
    __shared__ float Ws[BK][BN];
    int m0 = blockIdx.x * BM;
    int n0 = blockIdx.y * BN;
    int tid = threadIdx.x;
    int tm = tid >> 4, tn = tid & 15;
    int Ktot = K1 + K2;
    float acc[4][4] = {};
    for (int kt = 0; kt < Ktot; kt += BK) {
#pragma unroll
        for (int q = 0; q < 4; q++) {
            int idx = tid + q * 256;
            int row = idx >> 4;
            int kk = idx & 15;
            int m = m0 + row, k = kt + kk;
            float v = 0.f;
            if (m < M && k < Ktot)
                v = (k < K1) ? A1[(size_t)m * K1 + k] : A2[(size_t)m * K2 + (k - K1)];
            As[kk][row] = v;
        }
#pragma unroll
        for (int q = 0; q < 4; q++) {
            int idx = tid + q * 256;
            int kk = idx >> 6;
            int n = idx & 63;
            int k = kt + kk, nn = n0 + n;
            float v = 0.f;
            if (k < Ktot && nn < J)
                v = (k < K1) ? W1[(size_t)k * J + nn] : W2[(size_t)(k - K1) * J + nn];
            Ws[kk][n] = v;
        }
        __syncthreads();
#pragma unroll
        for (int k = 0; k < BK; k++) {
            float av[4], wv[4];
#pragma unroll
            for (int i = 0; i < 4; i++) av[i] = As[k][tm * 4 + i];
#pragma unroll
            for (int j = 0; j < 4; j++) wv[j] = Ws[k][tn * 4 + j];
#pragma unroll
            for (int i = 0; i < 4; i++)
#pragma unroll
                for (int j = 0; j < 4; j++) acc[i][j] += av[i] * wv[j];
        }
        __syncthreads();
    }
#pragma unroll
    for (int i = 0; i < 4; i++) {
        int m = m0 + tm * 4 + i;
        if (m >= M) continue;
#pragma unroll
        for (int j = 0; j < 4; j++) {
            int n = n0 + tn * 4 + j;
            if (n >= J) continue;
            float v = acc[i][j] + bias[n];
            if (ACT == 1) v = fmaxf(v, 0.f);
            C[(size_t)m * J + n] = v;
        }
    }
}

// ================= fused decoder =================
__global__ __launch_bounds__(256) void decoder_fused(
        const float* __restrict__ e0, const float* __restrict__ i1,
        const float* __restrict__ i2, const float* __restrict__ W0,
        const float* __restrict__ b0, const float* __restrict__ Wout,
        const float* __restrict__ bout, float* __restrict__ out, int N) {
    int ch = blockIdx.y;
    __shared__ float As[96][68];
    __shared__ float Ws[96 * 64];
    __shared__ float sb0[64];
    __shared__ float sWo[64];
    __shared__ float red[64][17];
    int tid = threadIdx.x;
    int m0 = blockIdx.x * 64;

    for (int idx = tid; idx < 96 * 64; idx += 256) Ws[idx] = W0[ch * 96 * 64 + idx];
    if (tid < 64) {
        sb0[tid] = b0[ch * 64 + tid];
        sWo[tid] = Wout[ch * 64 + tid];
    }
    for (int idx = tid; idx < 64 * 96; idx += 256) {
        int row = idx / 96;
        int k = idx % 96;
        int m = m0 + row;
        float v = 0.f;
        if (m < N) {
            const float* base = (k < 32) ? e0 : (k < 64 ? i1 : i2);
            v = base[(size_t)m * 96 + ch * 32 + (k & 31)];
        }
        As[k][row] = v;
    }
    __syncthreads();

    int tm = tid >> 4, tn = tid & 15;
    float acc[4][4] = {};
#pragma unroll
    for (int k = 0; k < 96; k++) {
        float4 a4 = *(const float4*)(&As[k][tm * 4]);
        float4 w4 = *(const float4*)(&Ws[k * 64 + tn * 4]);
        acc[0][0] += a4.x * w4.x; acc[0][1] += a4.x * w4.y; acc[0][2] += a4.x * w4.z; acc[0][3] += a4.x * w4.w;
        acc[1][0] += a4.y * w4.x; acc[1][1] += a4.y * w4.y; acc[1][2] += a4.y * w4.z; acc[1][3] += a4.y * w4.w;
        acc[2][0] += a4.z * w4.x; acc[2][1] += a4.z * w4.y; acc[2][2] += a4.z * w4.z; acc[2][3] += a4.z * w4.w;
        acc[3][0] += a4.w * w4.x; acc[3][1] += a4.w * w4.y; acc[3][2] += a4.w * w4.z; acc[3][3] += a4.w * w4.w;
    }
    float part[4];
#pragma unroll
    for (int i = 0; i < 4; i++) {
        float p = 0.f;
#pragma unroll
        for (int j = 0; j < 4; j++) {
            float h = acc[i][j] + sb0[tn * 4 + j];
            h = h > 0.f ? h : (expf(h) - 1.0f);
            p += h * sWo[tn * 4 + j];
        }
        part[i] = p;
    }
#pragma unroll
    for (int i = 0; i < 4; i++) red[tm * 4 + i][tn] = part[i];
    __syncthreads();
    if (tid < 64) {
        float s = 0.f;
#pragma unroll
        for (int t = 0; t < 16; t++) s += red[tid][t];
        int m = m0 + tid;
        if (m < N) out[(size_t)m * 3 + ch] = s + bout[ch];
    }
}

// ================= host launch =================

extern "C" void kernel_launch(void* const* d_in, const int* in_sizes, int n_in,
                              void* d_out, int out_size, void* d_ws, size_t ws_size,
                              hipStream_t stream) {
    const float* x0 = (const float*)d_in[0];
    const float* x1 = (const float*)d_in[1];
    const float* x2 = (const float*)d_in[2];
    const int* ei0 = (const int*)d_in[3];
    const int* ei1 = (const int*)d_in[4];
    const int* ei2 = (const int*)d_in[5];
    const int* A1r = (const int*)d_in[6];
    const int* A1c = (const int*)d_in[7];
    const float* A1v = (const float*)d_in[8];
    const int* A2r = (const int*)d_in[9];
    const int* A2c = (const int*)d_in[10];
    const float* A2v = (const float*)d_in[11];
    const float* c1Wrel = (const float*)d_in[12];
    const float* c1brel = (const float*)d_in[13];
    const float* c1Wroot = (const float*)d_in[14];
    const float* c2Wrel = (const float*)d_in[15];
    const float* c2brel = (const float*)d_in[16];
    const float* c2Wroot = (const float*)d_in[17];
    const float* linW = (const float*)d_in[18];
    const float* linb = (const float*)d_in[19];
    const float* dW0 = (const float*)d_in[20];
    const float* db0 = (const float*)d_in[21];
    const float* dWout = (const float*)d_in[22];
    const float* dbout = (const float*)d_in[23];
    float* out = (float*)d_out;

    // ---- workspace layout (float elements) ----
    float* ws = (float*)d_ws;
    float* h1 = ws;                   // 6.4M  (N0*128)
    float* agg = ws + 6400000;        // 6.4M
    float* h2 = ws + 12800000;        // 6.4M
    float* e0 = ws + 19200000;        // 4.8M  (N0*96)
    float* e1 = ws + 24000000;        // 1.2M
    float* e2 = ws + 25200000;        // 0.3M
    float* i1 = ws;                   // overlay h1 (valid after encoder phase)
    float* i2 = ws + 4800000;         // overlay h1/agg
    int* ibase = (int*)(ws + 25500000);
    int* cnt = ibase;                 // 50001
    int* offs = ibase + 50001;        // 50001
    int* csrc = ibase + 100002;       // 800000 (also ccol for interp)
    float* cval = (float*)(ibase + 900002);  // 200000
    int* extra = ibase + 1100002;
    int* bsum = extra;                // 32
    int* bexcl = extra + 32;          // 32
    unsigned short* c2hi = (unsigned short*)(extra + 64);  // 98304 ushort
    unsigned short* c2lo = c2hi + 98304;
    unsigned short* lhi = c2lo + 98304;                    // 36864
    unsigned short* llo = lhi + 36864;

    const float* xs[3] = {x0, x1, x2};
    const int* eis[3] = {ei0, ei1, ei2};
    const int Ns[3] = {N0, N1, N2};
    const int Es[3] = {800000, 200000, 50000};
    float* es[3] = {e0, e1, e2};

    hipMemsetAsync(cnt, 0, (size_t)N0 * sizeof(int), stream);
    conv_weights<<<(135168 + 255) / 256, 256, 0, stream>>>(c2Wrel, c2Wroot, linW,
                                                           c2hi, c2lo, lhi, llo);

    for (int i = 0; i < 3; i++) {
        int N = Ns[i], E = Es[i];
        const float* x = xs[i];
        const int* src = eis[i];
        const int* dst = eis[i] + E;
        int G = (N + 2047) / 2048;

        // CSR build by dst
        count_k<<<(E + 255) / 256, 256, 0, stream>>>(dst, cnt, E);
        scan_partial<<<G, 256, 0, stream>>>(cnt, bsum, N);
        scan_blocksums<<<1, 64, 0, stream>>>(bsum, bexcl, &offs[N], G);
        scan_final<<<G, 256, 0, stream>>>(cnt, offs, bexcl, N);
        fill_csr<<<(E + 255) / 256, 256, 0, stream>>>(src, dst, offs, csrc, E);

        // conv1 (K=12, fp32 path)
        gather6<<<(N + 255) / 256, 256, 0, stream>>>(x, offs, csrc, agg, N);
        dim3 g1((N + 63) / 64, 2);
        dualgemm<1><<<g1, 256, 0, stream>>>(agg, x, c1Wrel + i * 6 * 128,
                                            c1Wroot + i * 6 * 128, c1brel + i * 128,
                                            h1, N, 6, 6, 128);

        // conv2 (split-bf16 MFMA)
        gatherH<<<((size_t)N * 32 + 255) / 256, 256, 0, stream>>>(h1, offs, csrc, agg, N);
        mfma_dualgemm<1><<<(N + 63) / 64, 256, 0, stream>>>(
            agg, h1, c2hi + i * 32768, c2lo + i * 32768, c2brel + i * 128,
            h2, N, 128, 128, 128);

        // lin: 128 -> 96 (split-bf16 MFMA)
        mfma_dualgemm<0><<<(N + 63) / 64, 256, 0, stream>>>(
            h2, h2, lhi + i * 12288, llo + i * 12288, linb + i * 96,
            es[i], N, 128, 0, 96);
    }

    // ---- interpolation via CSR gather ----
    const int* Ars[2] = {A1r, A2r};
    const int* Acs[2] = {A1c, A2c};
    const float* Avs[2] = {A1v, A2v};
    const float* Aes[2] = {e1, e2};
    float* Ais[2] = {i1, i2};
    int G0 = (N0 + 2047) / 2048;
    for (int a = 0; a < 2; a++) {
        count_k<<<(NNZ + 255) / 256, 256, 0, stream>>>(Ars[a], cnt, NNZ);
        scan_partial<<<G0, 256, 0, stream>>>(cnt, bsum, N0);
        scan_blocksums<<<1, 64, 0, stream>>>(bsum, bexcl, &offs[N0], G0);
        scan_final<<<G0, 256, 0, stream>>>(cnt, offs, bexcl, N0);
        fill_csr_v<<<(NNZ + 255) / 256, 256, 0, stream>>>(Ars[a], Acs[a], Avs[a], offs,
                                                          csrc, cval, NNZ);
        interp_gather<<<((size_t)N0 * 24 + 255) / 256, 256, 0, stream>>>(
            Aes[a], offs, csrc, cval, Ais[a], N0);
    }

    // ---- fused decoder ----
    dim3 gd((N0 + 63) / 64, 3);
    decoder_fused<<<gd, 256, 0, stream>>>(e0, i1, i2, dW0, db0, dWout, dbout, out, N0);
}

// Round 6
// 469.748 us; speedup vs baseline: 6.1146x; 1.4736x over previous
//
#include <hip/hip_runtime.h>
#include <math.h>

#define N0 50000
#define N1 12500
#define N2 3125
#define NNZ 200000
#define NE0 800000
#define NE1 200000
#define NE2 50000
#define NT 65625           // N0+N1+N2
#define SEG_TOT 165625     // NT + 2*N0
#define EDGE_TOT 1050000   // NE0+NE1+NE2
#define ITEM_TOT 1450000   // EDGE_TOT + 2*NNZ

typedef __attribute__((ext_vector_type(8))) short short8;
typedef __attribute__((ext_vector_type(8))) unsigned short ushort8;
typedef __attribute__((ext_vector_type(4))) float floatx4;

__device__ inline void split_bf16(float x, unsigned short& hi, unsigned short& lo) {
    unsigned xb = __float_as_uint(x);
    hi = (unsigned short)(xb >> 16);
    float hf = __uint_as_float((unsigned)hi << 16);
    lo = (unsigned short)(__float_as_uint(x - hf) >> 16);
}

// split 8 contiguous fp32 (LDS) into hi/lo bf16 frags
__device__ inline void split8(const float* p, short8& hi, short8& lo) {
    float4 u0 = *(const float4*)p;
    float4 u1 = *(const float4*)(p + 4);
    float f[8] = {u0.x, u0.y, u0.z, u0.w, u1.x, u1.y, u1.z, u1.w};
#pragma unroll
    for (int j = 0; j < 8; j++) {
        unsigned short h, l;
        split_bf16(f[j], h, l);
        hi[j] = (short)h; lo[j] = (short)l;
    }
}

// ================= batched CSR build =================
// cnt/seg space: [0,50000) L0 nodes, [50000,62500) L1, [62500,65625) L2,
// [65625,115625) interp1 rows, [115625,165625) interp2 rows.

__global__ void count_all(const int* __restrict__ ei0, const int* __restrict__ ei1,
                          const int* __restrict__ ei2, const int* __restrict__ A1r,
                          const int* __restrict__ A2r, int* __restrict__ cnt) {
    int t = blockIdx.x * blockDim.x + threadIdx.x;
    if (t >= ITEM_TOT) return;
    int j;
    if (t < NE0) j = ei0[NE0 + t];
    else if (t < NE0 + NE1) j = 50000 + ei1[NE1 + (t - NE0)];
    else if (t < EDGE_TOT) j = 62500 + ei2[NE2 + (t - (NE0 + NE1))];
    else if (t < EDGE_TOT + NNZ) j = NT + A1r[t - EDGE_TOT];
    else j = NT + N0 + A2r[t - (EDGE_TOT + NNZ)];
    atomicAdd(&cnt[j], 1);
}

// 3-phase scan, 4096 elems/block (256 thr x 16). offs[i+1] = excl prefix of i; offs[0]=0.
__global__ __launch_bounds__(256) void scan_partial(const int* __restrict__ cnt,
                                                    int* __restrict__ bsum,
                                                    int* __restrict__ offs, int n) {
    __shared__ int wsum[4];
    int base = blockIdx.x * 4096 + threadIdx.x * 16;
    int s = 0;
#pragma unroll
    for (int q = 0; q < 16; q++) { int i = base + q; if (i < n) s += cnt[i]; }
#pragma unroll
    for (int off = 32; off > 0; off >>= 1) s += __shfl_down(s, off, 64);
    int lane = threadIdx.x & 63, wid = threadIdx.x >> 6;
    if (lane == 0) wsum[wid] = s;
    __syncthreads();
    if (threadIdx.x == 0) {
        bsum[blockIdx.x] = wsum[0] + wsum[1] + wsum[2] + wsum[3];
        if (blockIdx.x == 0) offs[0] = 0;
    }
}

__global__ void scan_blocksums(const int* __restrict__ bsum, int* __restrict__ bexcl, int G) {
    int lane = threadIdx.x;
    int v = (lane < G) ? bsum[lane] : 0;
    int s = v;
#pragma unroll
    for (int off = 1; off < 64; off <<= 1) {
        int t = __shfl_up(s, off, 64);
        if (lane >= off) s += t;
    }
    if (lane < G) bexcl[lane] = s - v;
}

__global__ __launch_bounds__(256) void scan_final(int* __restrict__ cnt, int* __restrict__ offs,
                                                  const int* __restrict__ bexcl, int n) {
    __shared__ int wsum[4];
    int base = blockIdx.x * 4096 + threadIdx.x * 16;
    int lane = threadIdx.x & 63, wid = threadIdx.x >> 6;
    int v[16], ts = 0;
#pragma unroll
    for (int q = 0; q < 16; q++) {
        int i = base + q;
        v[q] = (i < n) ? cnt[i] : 0;
        if (i < n) cnt[i] = 0;
        ts += v[q];
    }
    int s = ts;
#pragma unroll
    for (int off = 1; off < 64; off <<= 1) {
        int t = __shfl_up(s, off, 64);
        if (lane >= off) s += t;
    }
    if (lane == 63) wsum[wid] = s;
    __syncthreads();
    int woff = 0;
    for (int w = 0; w < wid; w++) woff += wsum[w];
    int run = bexcl[blockIdx.x] + woff + (s - ts);
#pragma unroll
    for (int q = 0; q < 16; q++) {
        int i = base + q;
        if (i < n) offs[i + 1] = run;
        run += v[q];
    }
}

// fill: cursor = offs[seg+1] (initially start_seg). After fill offs[j]/offs[j+1] = [start,end) of seg j.
__global__ void fill_all(const int* __restrict__ ei0, const int* __restrict__ ei1,
                         const int* __restrict__ ei2,
                         const int* __restrict__ A1r, const int* __restrict__ A1c,
                         const float* __restrict__ A1v,
                         const int* __restrict__ A2r, const int* __restrict__ A2c,
                         const float* __restrict__ A2v,
                         int* __restrict__ offs, int* __restrict__ csrc,
                         float* __restrict__ cval) {
    int t = blockIdx.x * blockDim.x + threadIdx.x;
    if (t >= ITEM_TOT) return;
    if (t < NE0) {
        int p = atomicAdd(&offs[ei0[NE0 + t] + 1], 1);
        csrc[p] = ei0[t];
    } else if (t < NE0 + NE1) {
        int e = t - NE0;
        int p = atomicAdd(&offs[50000 + ei1[NE1 + e] + 1], 1);
        csrc[p] = ei1[e];
    } else if (t < EDGE_TOT) {
        int e = t - (NE0 + NE1);
        int p = atomicAdd(&offs[62500 + ei2[NE2 + e] + 1], 1);
        csrc[p] = ei2[e];
    } else if (t < EDGE_TOT + NNZ) {
        int k = t - EDGE_TOT;
        int p = atomicAdd(&offs[NT + A1r[k] + 1], 1);
        csrc[p] = A1c[k];
        cval[p - EDGE_TOT] = A1v[k];
    } else {
        int k = t - (EDGE_TOT + NNZ);
        int p = atomicAdd(&offs[NT + N0 + A2r[k] + 1], 1);
        csrc[p] = A2c[k];
        cval[p - EDGE_TOT] = A2v[k];
    }
}

// ================= batched gathers =================

__global__ void gather6_b(const float* __restrict__ x0, const float* __restrict__ x1,
                          const float* __restrict__ x2, const int* __restrict__ offs,
                          const int* __restrict__ csrc, float* __restrict__ agg6) {
    int n = blockIdx.x * blockDim.x + threadIdx.x;
    if (n >= NT) return;
    const float* x = (n < 50000) ? x0 : (n < 62500 ? x1 : x2);
    float a0 = 0, a1 = 0, a2 = 0, a3 = 0, a4 = 0, a5 = 0;
    int b = offs[n], e = offs[n + 1];
    for (int j = b; j < e; j++) {
        const float* p = x + (size_t)csrc[j] * 6;
        a0 += p[0]; a1 += p[1]; a2 += p[2]; a3 += p[3]; a4 += p[4]; a5 += p[5];
    }
    float* o = agg6 + (size_t)n * 6;
    o[0] = a0; o[1] = a1; o[2] = a2; o[3] = a3; o[4] = a4; o[5] = a5;
}

__global__ __launch_bounds__(256) void gatherH_b(const float* __restrict__ h1,
                                                 const int* __restrict__ offs,
                                                 const int* __restrict__ csrc,
                                                 float* __restrict__ agg) {
    int t = blockIdx.x * blockDim.x + threadIdx.x;
    int n = t >> 5, g = t & 31;
    if (n >= NT) return;
    int nb = (n < 50000) ? 0 : (n < 62500 ? 50000 : 62500);
    float4 a = {0.f, 0.f, 0.f, 0.f};
    int b = offs[n], e = offs[n + 1];
    for (int j = b; j < e; j++) {
        float4 v = ((const float4*)(h1 + (size_t)(nb + csrc[j]) * 128))[g];
        a.x += v.x; a.y += v.y; a.z += v.z; a.w += v.w;
    }
    ((float4*)(agg + (size_t)n * 128))[g] = a;
}

__global__ __launch_bounds__(256) void interp_b(const float* __restrict__ ecat,
                                                const int* __restrict__ offs,
                                                const int* __restrict__ csrc,
                                                const float* __restrict__ cval,
                                                float* __restrict__ i1, float* __restrict__ i2) {
    int t = blockIdx.x * blockDim.x + threadIdx.x;
    int ng = t / 24, g = t % 24;
    if (ng >= 2 * N0) return;
    int a = (ng >= N0) ? 1 : 0;
    int nl = ng - a * N0;
    const float* e = ecat + (size_t)(a ? 62500 : 50000) * 96;
    float* ob = a ? i2 : i1;
    int seg = NT + ng;
    float4 s = {0.f, 0.f, 0.f, 0.f};
    int b = offs[seg], en = offs[seg + 1];
    for (int j = b; j < en; j++) {
        int c = csrc[j];
        float v = cval[j - EDGE_TOT];
        float4 w = ((const float4*)(e + (size_t)c * 96))[g];
        s.x += v * w.x; s.y += v * w.y; s.z += v * w.z; s.w += v * w.w;
    }
    ((float4*)(ob + (size_t)nl * 96))[g] = s;
}

// ================= weight preconvert =================
// c2 planes: [lvl][n][k] k<128 Wrel, else Wroot (K=256). lin planes: [lvl][n][k] K=128.
// decWt: fp32 [ch][col][k] (transposed dec_W0).
__global__ void conv_weights(const float* __restrict__ c2Wrel, const float* __restrict__ c2Wroot,
                             const float* __restrict__ linW, const float* __restrict__ dW0,
                             unsigned short* __restrict__ c2hi, unsigned short* __restrict__ c2lo,
                             unsigned short* __restrict__ lhi, unsigned short* __restrict__ llo,
                             float* __restrict__ decWt) {
    int t = blockIdx.x * blockDim.x + threadIdx.x;
    if (t < 98304) {
        int i = t / 32768, r = t % 32768;
        int n = r / 256, k = r % 256;
        float w = (k < 128) ? c2Wrel[i * 16384 + k * 128 + n]
                            : c2Wroot[i * 16384 + (k - 128) * 128 + n];
        unsigned short hi, lo;
        split_bf16(w, hi, lo);
        c2hi[t] = hi; c2lo[t] = lo;
    } else if (t < 135168) {
        int u = t - 98304;
        int i = u / 12288, r = u % 12288;
        int n = r / 128, k = r % 128;
        unsigned short hi, lo;
        split_bf16(linW[i * 12288 + k * 96 + n], hi, lo);
        lhi[u] = hi; llo[u] = lo;
    } else if (t < 153600) {
        int u = t - 135168;
        int chn = u / 6144, r = u % 6144;
        int col = r / 96, k = r % 96;
        decWt[u] = dW0[chn * 6144 + k * 64 + col];
    }
}

// ================= conv1 (fp32, K=12) batched over levels =================
__global__ __launch_bounds__(256) void conv1_b(
        const float* __restrict__ agg6, const float* __restrict__ x0,
        const float* __restrict__ x1, const float* __restrict__ x2,
        const float* __restrict__ Wrel, const float* __restrict__ Wroot,
        const float* __restrict__ brel, float* __restrict__ h1) {
    __shared__ float As[16][65];
    __shared__ float Ws[16][64];
    int bx = blockIdx.x;
    int l, lbk;
    if (bx < 782) { l = 0; lbk = bx; }
    else if (bx < 978) { l = 1; lbk = bx - 782; }
    else { l = 2; lbk = bx - 978; }
    int nb = (l == 0) ? 0 : (l == 1 ? 50000 : 62500);
    int M = (l == 0) ? N0 : (l == 1 ? N1 : N2);
    const float* xl = (l == 0) ? x0 : (l == 1 ? x1 : x2);
    const float* A1 = agg6 + (size_t)nb * 6;
    const float* W1 = Wrel + l * 768;
    const float* W2 = Wroot + l * 768;
    const float* bias = brel + l * 128;
    float* C = h1 + (size_t)nb * 128;
    int m0 = lbk * 64, n0 = blockIdx.y * 64;
    int tid = threadIdx.x;
    int tm = tid >> 4, tn = tid & 15;
    float acc[4][4] = {};
#pragma unroll
    for (int q = 0; q < 4; q++) {
        int idx = tid + q * 256;
        int row = idx >> 4, kk = idx & 15;
        int m = m0 + row;
        float v = 0.f;
        if (m < M && kk < 12)
            v = (kk < 6) ? A1[(size_t)m * 6 + kk] : xl[(size_t)m * 6 + kk - 6];
        As[kk][row] = v;
    }
#pragma unroll
    for (int q = 0; q < 4; q++) {
        int idx = tid + q * 256;
        int kk = idx >> 6, nn2 = idx & 63;
        float v = 0.f;
        if (kk < 12)
            v = (kk < 6) ? W1[kk * 128 + n0 + nn2] : W2[(kk - 6) * 128 + n0 + nn2];
        Ws[kk][nn2] = v;
    }
    __syncthreads();
#pragma unroll
    for (int k = 0; k < 12; k++) {
        float av[4], wv[4];
#pragma unroll
        for (int i = 0; i < 4; i++) av[i] = As[k][tm * 4 + i];
#pragma unroll
        for (int j = 0; j < 4; j++) wv[j] = Ws[k][tn * 4 + j];
#pragma unroll
        for (int i = 0; i < 4; i++)
#pragma unroll
            for (int j = 0; j < 4; j++) acc[i][j] += av[i] * wv[j];
    }
#pragma unroll
    for (int i = 0; i < 4; i++) {
        int m = m0 + tm * 4 + i;
        if (m >= M) continue;
#pragma unroll
        for (int j = 0; j < 4; j++) {
            int n = n0 + tn * 4 + j;
            float v = fmaxf(acc[i][j] + bias[n], 0.f);
            C[(size_t)m * 128 + n] = v;
        }
    }
}

// ================= fused conv2+lin (split-bf16 MFMA) =================
// phase1: h2 = relu([agg|h1] @ W2 + b2)  (K=256, J=128)  -> LDS hi/lo
// phase2: e = h2 @ linW + linb           (K=128, J=96)
__global__ __launch_bounds__(256) void conv2lin(
        const float* __restrict__ agg, const float* __restrict__ h1,
        const unsigned short* __restrict__ c2hi, const unsigned short* __restrict__ c2lo,
        const float* __restrict__ c2b,
        const unsigned short* __restrict__ lnhi, const unsigned short* __restrict__ lnlo,
        const float* __restrict__ lnb, float* __restrict__ ecat) {
    __shared__ unsigned short smem[25088];  // 50.2 KB union
    unsigned short* Ah = smem;              // 64*40
    unsigned short* Al = smem + 2560;
    unsigned short* Bh = smem + 5120;       // 128*40
    unsigned short* Bl = smem + 10240;
    unsigned short* Hh = smem;              // 64*136 (phase 2)
    unsigned short* Hl = smem + 8704;
    unsigned short* B2h = smem + 17408;     // 96*40
    unsigned short* B2l = smem + 21248;
    const int LDA = 40;

    int bx = blockIdx.x;
    int l, lbk;
    if (bx < 782) { l = 0; lbk = bx; }
    else if (bx < 978) { l = 1; lbk = bx - 782; }
    else { l = 2; lbk = bx - 978; }
    int nb = (l == 0) ? 0 : (l == 1 ? 50000 : 62500);
    int M = (l == 0) ? N0 : (l == 1 ? N1 : N2);
    const float* A1 = agg + (size_t)nb * 128;
    const float* A2 = h1 + (size_t)nb * 128;
    const unsigned short* W1h = c2hi + l * 32768;
    const unsigned short* W1l = c2lo + l * 32768;
    const float* b1 = c2b + l * 128;
    const unsigned short* W2h = lnhi + l * 12288;
    const unsigned short* W2l = lnlo + l * 12288;
    const float* b2 = lnb + l * 96;
    float* C = ecat + (size_t)nb * 96;
    int m0 = lbk * 64;

    int tid = threadIdx.x;
    int lane = tid & 63, wid = tid >> 6;
    int waveM = wid & 1, waveN = wid >> 1;
    int l15 = lane & 15, quad = lane >> 4;
    int arow = tid >> 2, acol = (tid & 3) * 8;
    int brow = tid >> 1, bcol = (tid & 1) * 16;

    floatx4 acc[2][4];
#pragma unroll
    for (int i = 0; i < 2; i++)
#pragma unroll
        for (int j = 0; j < 4; j++) acc[i][j] = (floatx4){0.f, 0.f, 0.f, 0.f};

    // ---- phase 1: K=256 ----
    for (int kt = 0; kt < 256; kt += 32) {
        __syncthreads();
        {
            float xv[8];
            int m = m0 + arow;
            if (m < M) {
                int kg = kt + acol;
                const float* src = (kg < 128) ? (A1 + (size_t)m * 128 + kg)
                                              : (A2 + (size_t)m * 128 + (kg - 128));
                float4 u0 = *(const float4*)src;
                float4 u1 = *(const float4*)(src + 4);
                xv[0] = u0.x; xv[1] = u0.y; xv[2] = u0.z; xv[3] = u0.w;
                xv[4] = u1.x; xv[5] = u1.y; xv[6] = u1.z; xv[7] = u1.w;
            } else {
#pragma unroll
                for (int q = 0; q < 8; q++) xv[q] = 0.f;
            }
            ushort8 hv, lv;
#pragma unroll
            for (int q = 0; q < 8; q++) {
                unsigned short h, lo2;
                split_bf16(xv[q], h, lo2);
                hv[q] = h; lv[q] = lo2;
            }
            *(ushort8*)(&Ah[arow * LDA + acol]) = hv;
            *(ushort8*)(&Al[arow * LDA + acol]) = lv;
        }
        {
            const unsigned short* ph = W1h + (size_t)brow * 256 + kt + bcol;
            const unsigned short* pl = W1l + (size_t)brow * 256 + kt + bcol;
            *(ushort8*)(&Bh[brow * LDA + bcol]) = *(const ushort8*)ph;
            *(ushort8*)(&Bh[brow * LDA + bcol + 8]) = *(const ushort8*)(ph + 8);
            *(ushort8*)(&Bl[brow * LDA + bcol]) = *(const ushort8*)pl;
            *(ushort8*)(&Bl[brow * LDA + bcol + 8]) = *(const ushort8*)(pl + 8);
        }
        __syncthreads();
        short8 af[2][2];
#pragma unroll
        for (int mt = 0; mt < 2; mt++) {
            int r = waveM * 32 + mt * 16 + l15;
            af[mt][0] = *(const short8*)(&Ah[r * LDA + quad * 8]);
            af[mt][1] = *(const short8*)(&Al[r * LDA + quad * 8]);
        }
#pragma unroll
        for (int nt = 0; nt < 4; nt++) {
            int c = waveN * 64 + nt * 16 + l15;
            short8 bh = *(const short8*)(&Bh[c * LDA + quad * 8]);
            short8 bl = *(const short8*)(&Bl[c * LDA + quad * 8]);
#pragma unroll
            for (int mt = 0; mt < 2; mt++) {
                acc[mt][nt] = __builtin_amdgcn_mfma_f32_16x16x32_bf16(af[mt][0], bh, acc[mt][nt], 0, 0, 0);
                acc[mt][nt] = __builtin_amdgcn_mfma_f32_16x16x32_bf16(af[mt][0], bl, acc[mt][nt], 0, 0, 0);
                acc[mt][nt] = __builtin_amdgcn_mfma_f32_16x16x32_bf16(af[mt][1], bh, acc[mt][nt], 0, 0, 0);
            }
        }
    }

    // ---- transition: h2 tile -> LDS hi/lo ----
    __syncthreads();  // all waves done reading phase-1 LDS
    {
        float bs1[4];
#pragma unroll
        for (int nt = 0; nt < 4; nt++) bs1[nt] = b1[waveN * 64 + nt * 16 + l15];
#pragma unroll
        for (int mt = 0; mt < 2; mt++)
#pragma unroll
            for (int nt = 0; nt < 4; nt++)
#pragma unroll
                for (int r = 0; r < 4; r++) {
                    int row = waveM * 32 + mt * 16 + quad * 4 + r;
                    int col = waveN * 64 + nt * 16 + l15;
                    float v = fmaxf(acc[mt][nt][r] + bs1[nt], 0.f);
                    unsigned short h, lo2;
                    split_bf16(v, h, lo2);
                    Hh[row * 136 + col] = h;
                    Hl[row * 136 + col] = lo2;
                }
    }

    // ---- phase 2: K=128, J=96 ----
    floatx4 acc2[2][3];
#pragma unroll
    for (int i = 0; i < 2; i++)
#pragma unroll
        for (int j = 0; j < 3; j++) acc2[i][j] = (floatx4){0.f, 0.f, 0.f, 0.f};

    for (int kt = 0; kt < 128; kt += 32) {
        __syncthreads();
        if (brow < 96) {
            const unsigned short* ph = W2h + (size_t)brow * 128 + kt + bcol;
            const unsigned short* pl = W2l + (size_t)brow * 128 + kt + bcol;
            *(ushort8*)(&B2h[brow * LDA + bcol]) = *(const ushort8*)ph;
            *(ushort8*)(&B2h[brow * LDA + bcol + 8]) = *(const ushort8*)(ph + 8);
            *(ushort8*)(&B2l[brow * LDA + bcol]) = *(const ushort8*)pl;
            *(ushort8*)(&B2l[brow * LDA + bcol + 8]) = *(const ushort8*)(pl + 8);
        }
        __syncthreads();
        short8 af2[2][2];
#pragma unroll
        for (int mt = 0; mt < 2; mt++) {
            int r = waveM * 32 + mt * 16 + l15;
            af2[mt][0] = *(const short8*)(&Hh[r * 136 + kt + quad * 8]);
            af2[mt][1] = *(const short8*)(&Hl[r * 136 + kt + quad * 8]);
        }
#pragma unroll
        for (int nt = 0; nt < 3; nt++) {
            int c = waveN * 48 + nt * 16 + l15;
            short8 bh = *(const short8*)(&B2h[c * LDA + quad * 8]);
            short8 bl = *(const short8*)(&B2l[c * LDA + quad * 8]);
#pragma unroll
            for (int mt = 0; mt < 2; mt++) {
                acc2[mt][nt] = __builtin_amdgcn_mfma_f32_16x16x32_bf16(af2[mt][0], bh, acc2[mt][nt], 0, 0, 0);
                acc2[mt][nt] = __builtin_amdgcn_mfma_f32_16x16x32_bf16(af2[mt][0], bl, acc2[mt][nt], 0, 0, 0);
                acc2[mt][nt] = __builtin_amdgcn_mfma_f32_16x16x32_bf16(af2[mt][1], bh, acc2[mt][nt], 0, 0, 0);
            }
        }
    }

    // ---- epilogue ----
    float bs2[3];
#pragma unroll
    for (int nt = 0; nt < 3; nt++) bs2[nt] = b2[waveN * 48 + nt * 16 + l15];
#pragma unroll
    for (int mt = 0; mt < 2; mt++)
#pragma unroll
        for (int r = 0; r < 4; r++) {
            int grow = m0 + waveM * 32 + mt * 16 + quad * 4 + r;
            if (grow >= M) continue;
#pragma unroll
            for (int nt = 0; nt < 3; nt++) {
                int col = waveN * 48 + nt * 16 + l15;
                C[(size_t)grow * 96 + col] = acc2[mt][nt][r] + bs2[nt];
            }
        }
}

// ================= MFMA decoder =================
// grid (782, 3). Block: 64 nodes x 64 hidden, K=96 one-shot, split-bf16.
__global__ __launch_bounds__(256) void decoder_mfma(
        const float* __restrict__ e0, const float* __restrict__ i1,
        const float* __restrict__ i2, const float* __restrict__ decWt,
        const float* __restrict__ b0, const float* __restrict__ Wout,
        const float* __restrict__ bout, float* __restrict__ out, int N) {
    __shared__ float As[6400];   // [row][k], pitch 100
    __shared__ float Bs[6400];   // [col][k], pitch 100
    __shared__ float red[64][2];
    __shared__ float sb0[64], sWo[64];
    int ch = blockIdx.y;
    int tid = threadIdx.x;
    int m0 = blockIdx.x * 64;

    for (int idx = tid; idx < 1536; idx += 256) {
        int col = idx / 24, k0 = (idx % 24) * 4;
        *(float4*)(&Bs[col * 100 + k0]) = *(const float4*)(decWt + ch * 6144 + col * 96 + k0);
    }
    if (tid < 64) { sb0[tid] = b0[ch * 64 + tid]; sWo[tid] = Wout[ch * 64 + tid]; }
    for (int idx = tid; idx < 1536; idx += 256) {
        int row = idx / 24, k0 = (idx % 24) * 4;
        int m = m0 + row;
        float4 v = {0.f, 0.f, 0.f, 0.f};
        if (m < N) {
            const float* base = (k0 < 32) ? e0 : (k0 < 64 ? i1 : i2);
            v = *(const float4*)(base + (size_t)m * 96 + ch * 32 + (k0 & 31));
        }
        *(float4*)(&As[row * 100 + k0]) = v;
    }
    __syncthreads();

    int lane = tid & 63, wid = tid >> 6;
    int waveM = wid & 1, waveN = wid >> 1;
    int l15 = lane & 15, quad = lane >> 4;
    floatx4 acc[2][2];
#pragma unroll
    for (int i = 0; i < 2; i++)
#pragma unroll
        for (int j = 0; j < 2; j++) acc[i][j] = (floatx4){0.f, 0.f, 0.f, 0.f};

#pragma unroll
    for (int kt = 0; kt < 96; kt += 32) {
        short8 ah[2], al[2];
#pragma unroll
        for (int mt = 0; mt < 2; mt++) {
            int r = waveM * 32 + mt * 16 + l15;
            split8(&As[r * 100 + kt + quad * 8], ah[mt], al[mt]);
        }
#pragma unroll
        for (int nt = 0; nt < 2; nt++) {
            int c = waveN * 32 + nt * 16 + l15;
            short8 bh, bl;
            split8(&Bs[c * 100 + kt + quad * 8], bh, bl);
#pragma unroll
            for (int mt = 0; mt < 2; mt++) {
                acc[mt][nt] = __builtin_amdgcn_mfma_f32_16x16x32_bf16(ah[mt], bh, acc[mt][nt], 0, 0, 0);
                acc[mt][nt] = __builtin_amdgcn_mfma_f32_16x16x32_bf16(ah[mt], bl, acc[mt][nt], 0, 0, 0);
                acc[mt][nt] = __builtin_amdgcn_mfma_f32_16x16x32_bf16(al[mt], bh, acc[mt][nt], 0, 0, 0);
            }
        }
    }

    // ELU + Wout dot + reduce
    float cb0[2], cwo[2];
#pragma unroll
    for (int nt = 0; nt < 2; nt++) {
        int col = waveN * 32 + nt * 16 + l15;
        cb0[nt] = sb0[col]; cwo[nt] = sWo[col];
    }
    float p[2][4];
#pragma unroll
    for (int mt = 0; mt < 2; mt++)
#pragma unroll
        for (int r = 0; r < 4; r++) {
            float s = 0.f;
#pragma unroll
            for (int nt = 0; nt < 2; nt++) {
                float h = acc[mt][nt][r] + cb0[nt];
                h = h > 0.f ? h : (expf(h) - 1.0f);
                s += h * cwo[nt];
            }
            p[mt][r] = s;
        }
#pragma unroll
    for (int mt = 0; mt < 2; mt++)
#pragma unroll
        for (int r = 0; r < 4; r++) {
#pragma unroll
            for (int msk = 1; msk < 16; msk <<= 1)
                p[mt][r] += __shfl_xor(p[mt][r], msk, 64);
        }
    if (l15 == 0) {
#pragma unroll
        for (int mt = 0; mt < 2; mt++)
#pragma unroll
            for (int r = 0; r < 4; r++) {
                int row = waveM * 32 + mt * 16 + quad * 4 + r;
                red[row][waveN] = p[mt][r];
            }
    }
    __syncthreads();
    if (tid < 64) {
        int m = m0 + tid;
        if (m < N) out[(size_t)m * 3 + ch] = red[tid][0] + red[tid][1] + bout[ch];
    }
}

// ================= host launch =================

extern "C" void kernel_launch(void* const* d_in, const int* in_sizes, int n_in,
                              void* d_out, int out_size, void* d_ws, size_t ws_size,
                              hipStream_t stream) {
    const float* x0 = (const float*)d_in[0];
    const float* x1 = (const float*)d_in[1];
    const float* x2 = (const float*)d_in[2];
    const int* ei0 = (const int*)d_in[3];
    const int* ei1 = (const int*)d_in[4];
    const int* ei2 = (const int*)d_in[5];
    const int* A1r = (const int*)d_in[6];
    const int* A1c = (const int*)d_in[7];
    const float* A1v = (const float*)d_in[8];
    const int* A2r = (const int*)d_in[9];
    const int* A2c = (const int*)d_in[10];
    const float* A2v = (const float*)d_in[11];
    const float* c1Wrel = (const float*)d_in[12];
    const float* c1brel = (const float*)d_in[13];
    const float* c1Wroot = (const float*)d_in[14];
    const float* c2Wrel = (const float*)d_in[15];
    const float* c2brel = (const float*)d_in[16];
    const float* c2Wroot = (const float*)d_in[17];
    const float* linW = (const float*)d_in[18];
    const float* linb = (const float*)d_in[19];
    const float* dW0 = (const float*)d_in[20];
    const float* db0 = (const float*)d_in[21];
    const float* dWout = (const float*)d_in[22];
    const float* dbout = (const float*)d_in[23];
    float* out = (float*)d_out;

    // ---- workspace (float words) ----
    float* ws = (float*)d_ws;
    float* agg6 = ws;                        // 400,000
    float* h1 = ws + 400000;                 // 8,400,000
    float* aggH = ws + 8800000;              // 8,400,000
    float* ecat = ws + 17200000;             // 6,300,000
    float* i1 = aggH;                        // overlay (free after conv2lin)
    float* i2 = ws + 400000;                 // overlay h1 (free after conv2lin)
    int* cnt = (int*)(ws + 23500000);        // 165,632
    int* offs = (int*)(ws + 23665632);       // 165,632 (uses 165,626)
    int* csrc = (int*)(ws + 23831264);       // 1,450,000
    int* bsum = (int*)(ws + 25281264);       // 64
    int* bexcl = (int*)(ws + 25281328);      // 64
    float* cval = ws + 25281392;             // 400,000
    unsigned short* c2hi = (unsigned short*)(ws + 25681392);  // 98,304 ushort
    unsigned short* c2lo = c2hi + 98304;                      // 98,304 ushort
    unsigned short* lnhi = c2lo + 98304;                      // 36,864 ushort
    unsigned short* lnlo = lnhi + 36864;                      // 36,864 ushort
    // ushort region total: 270,336 ushorts = 135,168 float words
    float* decWt = ws + 25681392 + 135168;   // 18,432 floats; ends at 25,834,992 (~103.3 MB)

    hipMemsetAsync(cnt, 0, (size_t)SEG_TOT * sizeof(int), stream);
    conv_weights<<<(153600 + 255) / 256, 256, 0, stream>>>(
        c2Wrel, c2Wroot, linW, dW0, c2hi, c2lo, lnhi, lnlo, decWt);

    // batched CSR
    int G = (SEG_TOT + 4095) / 4096;  // 41
    count_all<<<(ITEM_TOT + 255) / 256, 256, 0, stream>>>(ei0, ei1, ei2, A1r, A2r, cnt);
    scan_partial<<<G, 256, 0, stream>>>(cnt, bsum, offs, SEG_TOT);
    scan_blocksums<<<1, 64, 0, stream>>>(bsum, bexcl, G);
    scan_final<<<G, 256, 0, stream>>>(cnt, offs, bexcl, SEG_TOT);
    fill_all<<<(ITEM_TOT + 255) / 256, 256, 0, stream>>>(
        ei0, ei1, ei2, A1r, A1c, A1v, A2r, A2c, A2v, offs, csrc, cval);

    // encoder
    gather6_b<<<(NT + 255) / 256, 256, 0, stream>>>(x0, x1, x2, offs, csrc, agg6);
    dim3 g1(1027, 2);
    conv1_b<<<g1, 256, 0, stream>>>(agg6, x0, x1, x2, c1Wrel, c1Wroot, c1brel, h1);
    gatherH_b<<<((size_t)NT * 32 + 255) / 256, 256, 0, stream>>>(h1, offs, csrc, aggH);
    conv2lin<<<1027, 256, 0, stream>>>(aggH, h1, c2hi, c2lo, c2brel, lnhi, lnlo, linb, ecat);

    // interpolation (writes i1 over aggH, i2 over h1 — both dead now)
    interp_b<<<((size_t)2 * N0 * 24 + 255) / 256, 256, 0, stream>>>(
        ecat, offs, csrc, cval, i1, i2);

    // decoder
    dim3 gd(782, 3);
    decoder_mfma<<<gd, 256, 0, stream>>>(ecat, i1, i2, decWt, db0, dWout, dbout, out, N0);
}

// Round 7
// 346.566 us; speedup vs baseline: 8.2880x; 1.3554x over previous
//
#include <hip/hip_runtime.h>
#include <math.h>

#define N0 50000
#define N1 12500
#define N2 3125
#define NNZ 200000
#define NE0 800000
#define NE1 200000
#define NE2 50000
#define NT 65625           // N0+N1+N2
#define SEG_TOT 165625     // NT + 2*N0
#define EDGE_TOT 1050000   // NE0+NE1+NE2
#define ITEM_TOT 1450000   // EDGE_TOT + 2*NNZ
#define NBUCK 324          // ceil(SEG_TOT/512)
#define SPB 512            // segs per bucket
#define NBLK 355           // ceil(ITEM_TOT/4096)

typedef __attribute__((ext_vector_type(8))) short short8;
typedef __attribute__((ext_vector_type(8))) unsigned short ushort8;
typedef __attribute__((ext_vector_type(4))) float floatx4;

__device__ inline void split_bf16(float x, unsigned short& hi, unsigned short& lo) {
    unsigned xb = __float_as_uint(x);
    hi = (unsigned short)(xb >> 16);
    float hf = __uint_as_float((unsigned)hi << 16);
    lo = (unsigned short)(__float_as_uint(x - hf) >> 16);
}

// split 8 contiguous fp32 (LDS) into hi/lo bf16 frags
__device__ inline void split8(const float* p, short8& hi, short8& lo) {
    float4 u0 = *(const float4*)p;
    float4 u1 = *(const float4*)(p + 4);
    float f[8] = {u0.x, u0.y, u0.z, u0.w, u1.x, u1.y, u1.z, u1.w};
#pragma unroll
    for (int j = 0; j < 8; j++) {
        unsigned short h, l;
        split_bf16(f[j], h, l);
        hi[j] = (short)h; lo[j] = (short)l;
    }
}

// ================= binned CSR build =================
// seg space: [0,50000) L0 nodes, [50000,62500) L1, [62500,65625) L2,
// [65625,115625) interp1 rows, [115625,165625) interp2 rows.

__device__ inline int item_seg(int t, const int* __restrict__ ei0,
                               const int* __restrict__ ei1, const int* __restrict__ ei2,
                               const int* __restrict__ A1r, const int* __restrict__ A2r) {
    if (t < NE0) return ei0[NE0 + t];
    if (t < NE0 + NE1) return 50000 + ei1[NE1 + (t - NE0)];
    if (t < EDGE_TOT) return 62500 + ei2[NE2 + (t - (NE0 + NE1))];
    if (t < EDGE_TOT + NNZ) return NT + A1r[t - EDGE_TOT];
    return NT + N0 + A2r[t - (EDGE_TOT + NNZ)];
}

// A: per-block bucket histogram -> hist_g[bucket*NBLK + blk]
__global__ __launch_bounds__(256) void bin_hist(const int* __restrict__ ei0,
        const int* __restrict__ ei1, const int* __restrict__ ei2,
        const int* __restrict__ A1r, const int* __restrict__ A2r,
        int* __restrict__ hist_g) {
    __shared__ int h[NBUCK];
    for (int i = threadIdx.x; i < NBUCK; i += 256) h[i] = 0;
    __syncthreads();
    int base = blockIdx.x * 4096;
#pragma unroll
    for (int q = 0; q < 16; q++) {
        int t = base + q * 256 + threadIdx.x;
        if (t < ITEM_TOT) atomicAdd(&h[item_seg(t, ei0, ei1, ei2, A1r, A2r) >> 9], 1);
    }
    __syncthreads();
    for (int i = threadIdx.x; i < NBUCK; i += 256) hist_g[i * NBLK + blockIdx.x] = h[i];
}

// B1: bucket totals
__global__ void bucket_tot_k(const int* __restrict__ hist_g, int* __restrict__ btot) {
    int b = blockIdx.x;
    int s = 0;
    for (int i = threadIdx.x; i < NBLK; i += 64) s += hist_g[b * NBLK + i];
#pragma unroll
    for (int o = 32; o > 0; o >>= 1) s += __shfl_down(s, o, 64);
    if (threadIdx.x == 0) btot[b] = s;
}

// B3: per-bucket exclusive scan of hist_g row + bucket_base
__global__ void hist_scan(int* __restrict__ hist_g, const int* __restrict__ btot,
                          int* __restrict__ bbase) {
    int b = blockIdx.x, lane = threadIdx.x;
    int s = 0;
    for (int j = lane; j < b; j += 64) s += btot[j];
#pragma unroll
    for (int o = 32; o > 0; o >>= 1) s += __shfl_down(s, o, 64);
    int base = __shfl(s, 0, 64);
    if (lane == 0) {
        bbase[b] = base;
        if (b == NBUCK - 1) bbase[NBUCK] = ITEM_TOT;
    }
    int v[6], ts = 0;
#pragma unroll
    for (int q = 0; q < 6; q++) {
        int i = lane * 6 + q;
        v[q] = (i < NBLK) ? hist_g[b * NBLK + i] : 0;
        ts += v[q];
    }
    int sc = ts;
#pragma unroll
    for (int o = 1; o < 64; o <<= 1) {
        int t2 = __shfl_up(sc, o, 64);
        if (lane >= o) sc += t2;
    }
    int run = base + sc - ts;
#pragma unroll
    for (int q = 0; q < 6; q++) {
        int i = lane * 6 + q;
        if (i < NBLK) hist_g[b * NBLK + i] = run;
        run += v[q];
    }
}

// C: scatter items into bucket-ordered packed array
__global__ __launch_bounds__(256) void bin_scatter(const int* __restrict__ ei0,
        const int* __restrict__ ei1, const int* __restrict__ ei2,
        const int* __restrict__ A1r, const int* __restrict__ A1c, const float* __restrict__ A1v,
        const int* __restrict__ A2r, const int* __restrict__ A2c, const float* __restrict__ A2v,
        const int* __restrict__ hist_g, int* __restrict__ bpacked, float* __restrict__ bval) {
    __shared__ int cur[NBUCK];
    for (int i = threadIdx.x; i < NBUCK; i += 256) cur[i] = hist_g[i * NBLK + blockIdx.x];
    __syncthreads();
    int base = blockIdx.x * 4096;
#pragma unroll
    for (int q = 0; q < 16; q++) {
        int t = base + q * 256 + threadIdx.x;
        if (t >= ITEM_TOT) continue;
        int seg, pay;
        float val = 0.f;
        bool isv = false;
        if (t < NE0) { seg = ei0[NE0 + t]; pay = ei0[t]; }
        else if (t < NE0 + NE1) { int e = t - NE0; seg = 50000 + ei1[NE1 + e]; pay = ei1[e]; }
        else if (t < EDGE_TOT) { int e = t - (NE0 + NE1); seg = 62500 + ei2[NE2 + e]; pay = ei2[e]; }
        else if (t < EDGE_TOT + NNZ) { int k = t - EDGE_TOT; seg = NT + A1r[k]; pay = A1c[k]; val = A1v[k]; isv = true; }
        else { int k = t - (EDGE_TOT + NNZ); seg = NT + N0 + A2r[k]; pay = A2c[k]; val = A2v[k]; isv = true; }
        int bk = seg >> 9;
        int p = atomicAdd(&cur[bk], 1);
        bpacked[p] = ((seg - (bk << 9)) << 16) | pay;  // seg_local<512, pay<65536
        if (isv) bval[p] = val;
    }
}

// E: per-bucket count + scan + fill; writes offs[seg]=start directly.
__global__ __launch_bounds__(256) void bucket_fill(const int* __restrict__ bpacked,
        const float* __restrict__ bval, const int* __restrict__ bbase,
        int* __restrict__ offs, int* __restrict__ csrc, float* __restrict__ cval) {
    __shared__ int cnt[SPB];
    __shared__ int wsum2[4];
    int b = blockIdx.x, tid = threadIdx.x;
    int segbase = b * SPB;
    int seglim = SEG_TOT - segbase;
    if (seglim > SPB) seglim = SPB;
    int ibeg = bbase[b], iend = bbase[b + 1];
    for (int i = tid; i < SPB; i += 256) cnt[i] = 0;
    __syncthreads();
    for (int i = ibeg + tid; i < iend; i += 256)
        atomicAdd(&cnt[bpacked[i] >> 16], 1);
    __syncthreads();
    int lane = tid & 63, wid = tid >> 6;
    int v0 = cnt[tid * 2], v1 = cnt[tid * 2 + 1];
    int ts = v0 + v1, sc = ts;
#pragma unroll
    for (int o = 1; o < 64; o <<= 1) {
        int t2 = __shfl_up(sc, o, 64);
        if (lane >= o) sc += t2;
    }
    if (lane == 63) wsum2[wid] = sc;
    __syncthreads();
    int woff = 0;
    for (int w = 0; w < wid; w++) woff += wsum2[w];
    int ex = ibeg + woff + sc - ts;  // start position of seg tid*2
    __syncthreads();
    cnt[tid * 2] = ex;
    cnt[tid * 2 + 1] = ex + v0;
    if (tid * 2 < seglim) offs[segbase + tid * 2] = ex;
    if (tid * 2 + 1 < seglim) offs[segbase + tid * 2 + 1] = ex + v0;
    if (b == NBUCK - 1 && tid == 0) offs[SEG_TOT] = ITEM_TOT;
    __syncthreads();
    for (int i = ibeg + tid; i < iend; i += 256) {
        int w2 = bpacked[i];
        int sl = w2 >> 16, pay = w2 & 0xffff;
        int p = atomicAdd(&cnt[sl], 1);
        csrc[p] = pay;
        if (segbase + sl >= NT) cval[p - EDGE_TOT] = bval[i];
    }
}

// ================= batched gathers =================
// segment n spans [offs[n], offs[n+1])

__global__ void gather6_b(const float* __restrict__ x0, const float* __restrict__ x1,
                          const float* __restrict__ x2, const int* __restrict__ offs,
                          const int* __restrict__ csrc, float* __restrict__ agg6) {
    int n = blockIdx.x * blockDim.x + threadIdx.x;
    if (n >= NT) return;
    const float* x = (n < 50000) ? x0 : (n < 62500 ? x1 : x2);
    float a0 = 0, a1 = 0, a2 = 0, a3 = 0, a4 = 0, a5 = 0;
    int b = offs[n], e = offs[n + 1];
    for (int j = b; j < e; j++) {
        const float* p = x + (size_t)csrc[j] * 6;
        a0 += p[0]; a1 += p[1]; a2 += p[2]; a3 += p[3]; a4 += p[4]; a5 += p[5];
    }
    float* o = agg6 + (size_t)n * 6;
    o[0] = a0; o[1] = a1; o[2] = a2; o[3] = a3; o[4] = a4; o[5] = a5;
}

__global__ __launch_bounds__(256) void gatherH_b(const float* __restrict__ h1,
                                                 const int* __restrict__ offs,
                                                 const int* __restrict__ csrc,
                                                 float* __restrict__ agg) {
    int t = blockIdx.x * blockDim.x + threadIdx.x;
    int n = t >> 5, g = t & 31;
    if (n >= NT) return;
    int nb = (n < 50000) ? 0 : (n < 62500 ? 50000 : 62500);
    float4 a = {0.f, 0.f, 0.f, 0.f};
    int b = offs[n], e = offs[n + 1];
    for (int j = b; j < e; j++) {
        float4 v = ((const float4*)(h1 + (size_t)(nb + csrc[j]) * 128))[g];
        a.x += v.x; a.y += v.y; a.z += v.z; a.w += v.w;
    }
    ((float4*)(agg + (size_t)n * 128))[g] = a;
}

__global__ __launch_bounds__(256) void interp_b(const float* __restrict__ ecat,
                                                const int* __restrict__ offs,
                                                const int* __restrict__ csrc,
                                                const float* __restrict__ cval,
                                                float* __restrict__ i1, float* __restrict__ i2) {
    int t = blockIdx.x * blockDim.x + threadIdx.x;
    int ng = t / 24, g = t % 24;
    if (ng >= 2 * N0) return;
    int a = (ng >= N0) ? 1 : 0;
    int nl = ng - a * N0;
    const float* e = ecat + (size_t)(a ? 62500 : 50000) * 96;
    float* ob = a ? i2 : i1;
    int seg = NT + ng;
    float4 s = {0.f, 0.f, 0.f, 0.f};
    int b = offs[seg], en = offs[seg + 1];
    for (int j = b; j < en; j++) {
        int c = csrc[j];
        float v = cval[j - EDGE_TOT];
        float4 w = ((const float4*)(e + (size_t)c * 96))[g];
        s.x += v * w.x; s.y += v * w.y; s.z += v * w.z; s.w += v * w.w;
    }
    ((float4*)(ob + (size_t)nl * 96))[g] = s;
}

// ================= weight preconvert =================
__global__ void conv_weights(const float* __restrict__ c2Wrel, const float* __restrict__ c2Wroot,
                             const float* __restrict__ linW, const float* __restrict__ dW0,
                             unsigned short* __restrict__ c2hi, unsigned short* __restrict__ c2lo,
                             unsigned short* __restrict__ lhi, unsigned short* __restrict__ llo,
                             float* __restrict__ decWt) {
    int t = blockIdx.x * blockDim.x + threadIdx.x;
    if (t < 98304) {
        int i = t / 32768, r = t % 32768;
        int n = r / 256, k = r % 256;
        float w = (k < 128) ? c2Wrel[i * 16384 + k * 128 + n]
                            : c2Wroot[i * 16384 + (k - 128) * 128 + n];
        unsigned short hi, lo;
        split_bf16(w, hi, lo);
        c2hi[t] = hi; c2lo[t] = lo;
    } else if (t < 135168) {
        int u = t - 98304;
        int i = u / 12288, r = u % 12288;
        int n = r / 128, k = r % 128;
        unsigned short hi, lo;
        split_bf16(linW[i * 12288 + k * 96 + n], hi, lo);
        lhi[u] = hi; llo[u] = lo;
    } else if (t < 153600) {
        int u = t - 135168;
        int chn = u / 6144, r = u % 6144;
        int col = r / 96, k = r % 96;
        decWt[u] = dW0[chn * 6144 + k * 64 + col];
    }
}

// ================= conv1 (fp32, K=12) batched over levels =================
__global__ __launch_bounds__(256) void conv1_b(
        const float* __restrict__ agg6, const float* __restrict__ x0,
        const float* __restrict__ x1, const float* __restrict__ x2,
        const float* __restrict__ Wrel, const float* __restrict__ Wroot,
        const float* __restrict__ brel, float* __restrict__ h1) {
    __shared__ float As[16][65];
    __shared__ float Ws[16][64];
    int bx = blockIdx.x;
    int l, lbk;
    if (bx < 782) { l = 0; lbk = bx; }
    else if (bx < 978) { l = 1; lbk = bx - 782; }
    else { l = 2; lbk = bx - 978; }
    int nb = (l == 0) ? 0 : (l == 1 ? 50000 : 62500);
    int M = (l == 0) ? N0 : (l == 1 ? N1 : N2);
    const float* xl = (l == 0) ? x0 : (l == 1 ? x1 : x2);
    const float* A1 = agg6 + (size_t)nb * 6;
    const float* W1 = Wrel + l * 768;
    const float* W2 = Wroot + l * 768;
    const float* bias = brel + l * 128;
    float* C = h1 + (size_t)nb * 128;
    int m0 = lbk * 64, n0 = blockIdx.y * 64;
    int tid = threadIdx.x;
    int tm = tid >> 4, tn = tid & 15;
    float acc[4][4] = {};
#pragma unroll
    for (int q = 0; q < 4; q++) {
        int idx = tid + q * 256;
        int row = idx >> 4, kk = idx & 15;
        int m = m0 + row;
        float v = 0.f;
        if (m < M && kk < 12)
            v = (kk < 6) ? A1[(size_t)m * 6 + kk] : xl[(size_t)m * 6 + kk - 6];
        As[kk][row] = v;
    }
#pragma unroll
    for (int q = 0; q < 4; q++) {
        int idx = tid + q * 256;
        int kk = idx >> 6, nn2 = idx & 63;
        float v = 0.f;
        if (kk < 12)
            v = (kk < 6) ? W1[kk * 128 + n0 + nn2] : W2[(kk - 6) * 128 + n0 + nn2];
        Ws[kk][nn2] = v;
    }
    __syncthreads();
#pragma unroll
    for (int k = 0; k < 12; k++) {
        float av[4], wv[4];
#pragma unroll
        for (int i = 0; i < 4; i++) av[i] = As[k][tm * 4 + i];
#pragma unroll
        for (int j = 0; j < 4; j++) wv[j] = Ws[k][tn * 4 + j];
#pragma unroll
        for (int i = 0; i < 4; i++)
#pragma unroll
            for (int j = 0; j < 4; j++) acc[i][j] += av[i] * wv[j];
    }
#pragma unroll
    for (int i = 0; i < 4; i++) {
        int m = m0 + tm * 4 + i;
        if (m >= M) continue;
#pragma unroll
        for (int j = 0; j < 4; j++) {
            int n = n0 + tn * 4 + j;
            float v = fmaxf(acc[i][j] + bias[n], 0.f);
            C[(size_t)m * 128 + n] = v;
        }
    }
}

// ================= fused conv2+lin (split-bf16 MFMA) =================
__global__ __launch_bounds__(256) void conv2lin(
        const float* __restrict__ agg, const float* __restrict__ h1,
        const unsigned short* __restrict__ c2hi, const unsigned short* __restrict__ c2lo,
        const float* __restrict__ c2b,
        const unsigned short* __restrict__ lnhi, const unsigned short* __restrict__ lnlo,
        const float* __restrict__ lnb, float* __restrict__ ecat) {
    __shared__ unsigned short smem[25088];  // 50.2 KB union
    unsigned short* Ah = smem;              // 64*40
    unsigned short* Al = smem + 2560;
    unsigned short* Bh = smem + 5120;       // 128*40
    unsigned short* Bl = smem + 10240;
    unsigned short* Hh = smem;              // 64*136 (phase 2)
    unsigned short* Hl = smem + 8704;
    unsigned short* B2h = smem + 17408;     // 96*40
    unsigned short* B2l = smem + 21248;
    const int LDA = 40;

    int bx = blockIdx.x;
    int l, lbk;
    if (bx < 782) { l = 0; lbk = bx; }
    else if (bx < 978) { l = 1; lbk = bx - 782; }
    else { l = 2; lbk = bx - 978; }
    int nb = (l == 0) ? 0 : (l == 1 ? 50000 : 62500);
    int M = (l == 0) ? N0 : (l == 1 ? N1 : N2);
    const float* A1 = agg + (size_t)nb * 128;
    const float* A2 = h1 + (size_t)nb * 128;
    const unsigned short* W1h = c2hi + l * 32768;
    const unsigned short* W1l = c2lo + l * 32768;
    const float* b1 = c2b + l * 128;
    const unsigned short* W2h = lnhi + l * 12288;
    const unsigned short* W2l = lnlo + l * 12288;
    const float* b2 = lnb + l * 96;
    float* C = ecat + (size_t)nb * 96;
    int m0 = lbk * 64;

    int tid = threadIdx.x;
    int lane = tid & 63, wid = tid >> 6;
    int waveM = wid & 1, waveN = wid >> 1;
    int l15 = lane & 15, quad = lane >> 4;
    int arow = tid >> 2, acol = (tid & 3) * 8;
    int brow = tid >> 1, bcol = (tid & 1) * 16;

    floatx4 acc[2][4];
#pragma unroll
    for (int i = 0; i < 2; i++)
#pragma unroll
        for (int j = 0; j < 4; j++) acc[i][j] = (floatx4){0.f, 0.f, 0.f, 0.f};

    // ---- phase 1: K=256 ----
    for (int kt = 0; kt < 256; kt += 32) {
        __syncthreads();
        {
            float xv[8];
            int m = m0 + arow;
            if (m < M) {
                int kg = kt + acol;
                const float* src = (kg < 128) ? (A1 + (size_t)m * 128 + kg)
                                              : (A2 + (size_t)m * 128 + (kg - 128));
                float4 u0 = *(const float4*)src;
                float4 u1 = *(const float4*)(src + 4);
                xv[0] = u0.x; xv[1] = u0.y; xv[2] = u0.z; xv[3] = u0.w;
                xv[4] = u1.x; xv[5] = u1.y; xv[6] = u1.z; xv[7] = u1.w;
            } else {
#pragma unroll
                for (int q = 0; q < 8; q++) xv[q] = 0.f;
            }
            ushort8 hv, lv;
#pragma unroll
            for (int q = 0; q < 8; q++) {
                unsigned short h, lo2;
                split_bf16(xv[q], h, lo2);
                hv[q] = h; lv[q] = lo2;
            }
            *(ushort8*)(&Ah[arow * LDA + acol]) = hv;
            *(ushort8*)(&Al[arow * LDA + acol]) = lv;
        }
        {
            const unsigned short* ph = W1h + (size_t)brow * 256 + kt + bcol;
            const unsigned short* pl = W1l + (size_t)brow * 256 + kt + bcol;
            *(ushort8*)(&Bh[brow * LDA + bcol]) = *(const ushort8*)ph;
            *(ushort8*)(&Bh[brow * LDA + bcol + 8]) = *(const ushort8*)(ph + 8);
            *(ushort8*)(&Bl[brow * LDA + bcol]) = *(const ushort8*)pl;
            *(ushort8*)(&Bl[brow * LDA + bcol + 8]) = *(const ushort8*)(pl + 8);
        }
        __syncthreads();
        short8 af[2][2];
#pragma unroll
        for (int mt = 0; mt < 2; mt++) {
            int r = waveM * 32 + mt * 16 + l15;
            af[mt][0] = *(const short8*)(&Ah[r * LDA + quad * 8]);
            af[mt][1] = *(const short8*)(&Al[r * LDA + quad * 8]);
        }
#pragma unroll
        for (int nt = 0; nt < 4; nt++) {
            int c = waveN * 64 + nt * 16 + l15;
            short8 bh = *(const short8*)(&Bh[c * LDA + quad * 8]);
            short8 bl = *(const short8*)(&Bl[c * LDA + quad * 8]);
#pragma unroll
            for (int mt = 0; mt < 2; mt++) {
                acc[mt][nt] = __builtin_amdgcn_mfma_f32_16x16x32_bf16(af[mt][0], bh, acc[mt][nt], 0, 0, 0);
                acc[mt][nt] = __builtin_amdgcn_mfma_f32_16x16x32_bf16(af[mt][0], bl, acc[mt][nt], 0, 0, 0);
                acc[mt][nt] = __builtin_amdgcn_mfma_f32_16x16x32_bf16(af[mt][1], bh, acc[mt][nt], 0, 0, 0);
            }
        }
    }

    // ---- transition: h2 tile -> LDS hi/lo ----
    __syncthreads();
    {
        float bs1[4];
#pragma unroll
        for (int nt = 0; nt < 4; nt++) bs1[nt] = b1[waveN * 64 + nt * 16 + l15];
#pragma unroll
        for (int mt = 0; mt < 2; mt++)
#pragma unroll
            for (int nt = 0; nt < 4; nt++)
#pragma unroll
                for (int r = 0; r < 4; r++) {
                    int row = waveM * 32 + mt * 16 + quad * 4 + r;
                    int col = waveN * 64 + nt * 16 + l15;
                    float v = fmaxf(acc[mt][nt][r] + bs1[nt], 0.f);
                    unsigned short h, lo2;
                    split_bf16(v, h, lo2);
                    Hh[row * 136 + col] = h;
                    Hl[row * 136 + col] = lo2;
                }
    }

    // ---- phase 2: K=128, J=96 ----
    floatx4 acc2[2][3];
#pragma unroll
    for (int i = 0; i < 2; i++)
#pragma unroll
        for (int j = 0; j < 3; j++) acc2[i][j] = (floatx4){0.f, 0.f, 0.f, 0.f};

    for (int kt = 0; kt < 128; kt += 32) {
        __syncthreads();
        if (brow < 96) {
            const unsigned short* ph = W2h + (size_t)brow * 128 + kt + bcol;
            const unsigned short* pl = W2l + (size_t)brow * 128 + kt + bcol;
            *(ushort8*)(&B2h[brow * LDA + bcol]) = *(const ushort8*)ph;
            *(ushort8*)(&B2h[brow * LDA + bcol + 8]) = *(const ushort8*)(ph + 8);
            *(ushort8*)(&B2l[brow * LDA + bcol]) = *(const ushort8*)pl;
            *(ushort8*)(&B2l[brow * LDA + bcol + 8]) = *(const ushort8*)(pl + 8);
        }
        __syncthreads();
        short8 af2[2][2];
#pragma unroll
        for (int mt = 0; mt < 2; mt++) {
            int r = waveM * 32 + mt * 16 + l15;
            af2[mt][0] = *(const short8*)(&Hh[r * 136 + kt + quad * 8]);
            af2[mt][1] = *(const short8*)(&Hl[r * 136 + kt + quad * 8]);
        }
#pragma unroll
        for (int nt = 0; nt < 3; nt++) {
            int c = waveN * 48 + nt * 16 + l15;
            short8 bh = *(const short8*)(&B2h[c * LDA + quad * 8]);
            short8 bl = *(const short8*)(&B2l[c * LDA + quad * 8]);
#pragma unroll
            for (int mt = 0; mt < 2; mt++) {
                acc2[mt][nt] = __builtin_amdgcn_mfma_f32_16x16x32_bf16(af2[mt][0], bh, acc2[mt][nt], 0, 0, 0);
                acc2[mt][nt] = __builtin_amdgcn_mfma_f32_16x16x32_bf16(af2[mt][0], bl, acc2[mt][nt], 0, 0, 0);
                acc2[mt][nt] = __builtin_amdgcn_mfma_f32_16x16x32_bf16(af2[mt][1], bh, acc2[mt][nt], 0, 0, 0);
            }
        }
    }

    // ---- epilogue ----
    float bs2[3];
#pragma unroll
    for (int nt = 0; nt < 3; nt++) bs2[nt] = b2[waveN * 48 + nt * 16 + l15];
#pragma unroll
    for (int mt = 0; mt < 2; mt++)
#pragma unroll
        for (int r = 0; r < 4; r++) {
            int grow = m0 + waveM * 32 + mt * 16 + quad * 4 + r;
            if (grow >= M) continue;
#pragma unroll
            for (int nt = 0; nt < 3; nt++) {
                int col = waveN * 48 + nt * 16 + l15;
                C[(size_t)grow * 96 + col] = acc2[mt][nt][r] + bs2[nt];
            }
        }
}

// ================= MFMA decoder =================
__global__ __launch_bounds__(256) void decoder_mfma(
        const float* __restrict__ e0, const float* __restrict__ i1,
        const float* __restrict__ i2, const float* __restrict__ decWt,
        const float* __restrict__ b0, const float* __restrict__ Wout,
        const float* __restrict__ bout, float* __restrict__ out, int N) {
    __shared__ float As[6400];   // [row][k], pitch 100
    __shared__ float Bs[6400];   // [col][k], pitch 100
    __shared__ float red[64][2];
    __shared__ float sb0[64], sWo[64];
    int ch = blockIdx.y;
    int tid = threadIdx.x;
    int m0 = blockIdx.x * 64;

    for (int idx = tid; idx < 1536; idx += 256) {
        int col = idx / 24, k0 = (idx % 24) * 4;
        *(float4*)(&Bs[col * 100 + k0]) = *(const float4*)(decWt + ch * 6144 + col * 96 + k0);
    }
    if (tid < 64) { sb0[tid] = b0[ch * 64 + tid]; sWo[tid] = Wout[ch * 64 + tid]; }
    for (int idx = tid; idx < 1536; idx += 256) {
        int row = idx / 24, k0 = (idx % 24) * 4;
        int m = m0 + row;
        float4 v = {0.f, 0.f, 0.f, 0.f};
        if (m < N) {
            const float* base = (k0 < 32) ? e0 : (k0 < 64 ? i1 : i2);
            v = *(const float4*)(base + (size_t)m * 96 + ch * 32 + (k0 & 31));
        }
        *(float4*)(&As[row * 100 + k0]) = v;
    }
    __syncthreads();

    int lane = tid & 63, wid = tid >> 6;
    int waveM = wid & 1, waveN = wid >> 1;
    int l15 = lane & 15, quad = lane >> 4;
    floatx4 acc[2][2];
#pragma unroll
    for (int i = 0; i < 2; i++)
#pragma unroll
        for (int j = 0; j < 2; j++) acc[i][j] = (floatx4){0.f, 0.f, 0.f, 0.f};

#pragma unroll
    for (int kt = 0; kt < 96; kt += 32) {
        short8 ah[2], al[2];
#pragma unroll
        for (int mt = 0; mt < 2; mt++) {
            int r = waveM * 32 + mt * 16 + l15;
            split8(&As[r * 100 + kt + quad * 8], ah[mt], al[mt]);
        }
#pragma unroll
        for (int nt = 0; nt < 2; nt++) {
            int c = waveN * 32 + nt * 16 + l15;
            short8 bh, bl;
            split8(&Bs[c * 100 + kt + quad * 8], bh, bl);
#pragma unroll
            for (int mt = 0; mt < 2; mt++) {
                acc[mt][nt] = __builtin_amdgcn_mfma_f32_16x16x32_bf16(ah[mt], bh, acc[mt][nt], 0, 0, 0);
                acc[mt][nt] = __builtin_amdgcn_mfma_f32_16x16x32_bf16(ah[mt], bl, acc[mt][nt], 0, 0, 0);
                acc[mt][nt] = __builtin_amdgcn_mfma_f32_16x16x32_bf16(al[mt], bh, acc[mt][nt], 0, 0, 0);
            }
        }
    }

    float cb0[2], cwo[2];
#pragma unroll
    for (int nt = 0; nt < 2; nt++) {
        int col = waveN * 32 + nt * 16 + l15;
        cb0[nt] = sb0[col]; cwo[nt] = sWo[col];
    }
    float p[2][4];
#pragma unroll
    for (int mt = 0; mt < 2; mt++)
#pragma unroll
        for (int r = 0; r < 4; r++) {
            float s = 0.f;
#pragma unroll
            for (int nt = 0; nt < 2; nt++) {
                float h = acc[mt][nt][r] + cb0[nt];
                h = h > 0.f ? h : (expf(h) - 1.0f);
                s += h * cwo[nt];
            }
            p[mt][r] = s;
        }
#pragma unroll
    for (int mt = 0; mt < 2; mt++)
#pragma unroll
        for (int r = 0; r < 4; r++) {
#pragma unroll
            for (int msk = 1; msk < 16; msk <<= 1)
                p[mt][r] += __shfl_xor(p[mt][r], msk, 64);
        }
    if (l15 == 0) {
#pragma unroll
        for (int mt = 0; mt < 2; mt++)
#pragma unroll
            for (int r = 0; r < 4; r++) {
                int row = waveM * 32 + mt * 16 + quad * 4 + r;
                red[row][waveN] = p[mt][r];
            }
    }
    __syncthreads();
    if (tid < 64) {
        int m = m0 + tid;
        if (m < N) out[(size_t)m * 3 + ch] = red[tid][0] + red[tid][1] + bout[ch];
    }
}

// ================= host launch =================

extern "C" void kernel_launch(void* const* d_in, const int* in_sizes, int n_in,
                              void* d_out, int out_size, void* d_ws, size_t ws_size,
                              hipStream_t stream) {
    const float* x0 = (const float*)d_in[0];
    const float* x1 = (const float*)d_in[1];
    const float* x2 = (const float*)d_in[2];
    const int* ei0 = (const int*)d_in[3];
    const int* ei1 = (const int*)d_in[4];
    const int* ei2 = (const int*)d_in[5];
    const int* A1r = (const int*)d_in[6];
    const int* A1c = (const int*)d_in[7];
    const float* A1v = (const float*)d_in[8];
    const int* A2r = (const int*)d_in[9];
    const int* A2c = (const int*)d_in[10];
    const float* A2v = (const float*)d_in[11];
    const float* c1Wrel = (const float*)d_in[12];
    const float* c1brel = (const float*)d_in[13];
    const float* c1Wroot = (const float*)d_in[14];
    const float* c2Wrel = (const float*)d_in[15];
    const float* c2brel = (const float*)d_in[16];
    const float* c2Wroot = (const float*)d_in[17];
    const float* linW = (const float*)d_in[18];
    const float* linb = (const float*)d_in[19];
    const float* dW0 = (const float*)d_in[20];
    const float* db0 = (const float*)d_in[21];
    const float* dWout = (const float*)d_in[22];
    const float* dbout = (const float*)d_in[23];
    float* out = (float*)d_out;

    // ---- workspace (float words) ----
    float* ws = (float*)d_ws;
    float* agg6 = ws;                        // 400,000
    float* h1 = ws + 400000;                 // 8,400,000
    float* aggH = ws + 8800000;              // 8,400,000
    float* ecat = ws + 17200000;             // 6,300,000
    float* i1 = aggH;                        // overlay (free after conv2lin)
    float* i2 = ws + 400000;                 // overlay h1 (free after conv2lin)
    // binned intermediates overlay aggH (dead until gatherH_b)
    int* bpacked = (int*)(ws + 8800000);     // 1,450,000
    float* bval = ws + 8800000 + 1450000;    // 1,450,000 (ends 11,700,000 < 17,200,000)
    int* hist_g = (int*)(ws + 23500000);     // NBUCK*NBLK = 115,020
    int* btot = (int*)(ws + 23615020);       // 324
    int* bbase = (int*)(ws + 23615344);      // 325
    int* offs = (int*)(ws + 23665632);       // 165,626
    int* csrc = (int*)(ws + 23831264);       // 1,450,000
    float* cval = ws + 25281392;             // 400,000
    unsigned short* c2hi = (unsigned short*)(ws + 25681392);  // 98,304 ushort
    unsigned short* c2lo = c2hi + 98304;
    unsigned short* lnhi = c2lo + 98304;                      // 36,864 ushort
    unsigned short* lnlo = lnhi + 36864;
    float* decWt = ws + 25681392 + 135168;   // 18,432 floats; ends ~25,834,992 (~103.3 MB)

    conv_weights<<<(153600 + 255) / 256, 256, 0, stream>>>(
        c2Wrel, c2Wroot, linW, dW0, c2hi, c2lo, lnhi, lnlo, decWt);

    // ---- binned CSR build ----
    bin_hist<<<NBLK, 256, 0, stream>>>(ei0, ei1, ei2, A1r, A2r, hist_g);
    bucket_tot_k<<<NBUCK, 64, 0, stream>>>(hist_g, btot);
    hist_scan<<<NBUCK, 64, 0, stream>>>(hist_g, btot, bbase);
    bin_scatter<<<NBLK, 256, 0, stream>>>(ei0, ei1, ei2, A1r, A1c, A1v,
                                          A2r, A2c, A2v, hist_g, bpacked, bval);
    bucket_fill<<<NBUCK, 256, 0, stream>>>(bpacked, bval, bbase, offs, csrc, cval);

    // ---- encoder ----
    gather6_b<<<(NT + 255) / 256, 256, 0, stream>>>(x0, x1, x2, offs, csrc, agg6);
    dim3 g1(1027, 2);
    conv1_b<<<g1, 256, 0, stream>>>(agg6, x0, x1, x2, c1Wrel, c1Wroot, c1brel, h1);
    gatherH_b<<<((size_t)NT * 32 + 255) / 256, 256, 0, stream>>>(h1, offs, csrc, aggH);
    conv2lin<<<1027, 256, 0, stream>>>(aggH, h1, c2hi, c2lo, c2brel, lnhi, lnlo, linb, ecat);

    // ---- interpolation (writes i1 over aggH, i2 over h1 — both dead now) ----
    interp_b<<<((size_t)2 * N0 * 24 + 255) / 256, 256, 0, stream>>>(
        ecat, offs, csrc, cval, i1, i2);

    // ---- decoder ----
    dim3 gd(782, 3);
    decoder_mfma<<<gd, 256, 0, stream>>>(ecat, i1, i2, decWt, db0, dWout, dbout, out, N0);
}

// Round 8
// 337.576 us; speedup vs baseline: 8.5087x; 1.0266x over previous
//
#include <hip/hip_runtime.h>
#include <math.h>

#define N0 50000
#define N1 12500
#define N2 3125
#define NNZ 200000
#define NE0 800000
#define NE1 200000
#define NE2 50000
#define NT 65625           // N0+N1+N2
#define SEG_TOT 165625     // NT + 2*N0
#define EDGE_TOT 1050000   // NE0+NE1+NE2
#define ITEM_TOT 1450000   // EDGE_TOT + 2*NNZ
#define NBUCK 324          // ceil(SEG_TOT/512)
#define SPB 512            // segs per bucket
#define NBLK 355           // ceil(ITEM_TOT/4096)

typedef __attribute__((ext_vector_type(8))) short short8;
typedef __attribute__((ext_vector_type(8))) unsigned short ushort8;
typedef __attribute__((ext_vector_type(4))) float floatx4;

__device__ inline void split_bf16(float x, unsigned short& hi, unsigned short& lo) {
    unsigned xb = __float_as_uint(x);
    hi = (unsigned short)(xb >> 16);
    float hf = __uint_as_float((unsigned)hi << 16);
    lo = (unsigned short)(__float_as_uint(x - hf) >> 16);
}

// split 8 contiguous fp32 (LDS) into hi/lo bf16 frags
__device__ inline void split8(const float* p, short8& hi, short8& lo) {
    float4 u0 = *(const float4*)p;
    float4 u1 = *(const float4*)(p + 4);
    float f[8] = {u0.x, u0.y, u0.z, u0.w, u1.x, u1.y, u1.z, u1.w};
#pragma unroll
    for (int j = 0; j < 8; j++) {
        unsigned short h, l;
        split_bf16(f[j], h, l);
        hi[j] = (short)h; lo[j] = (short)l;
    }
}

// ================= binned CSR build =================
// seg space: [0,50000) L0 nodes, [50000,62500) L1, [62500,65625) L2,
// [65625,115625) interp1 rows, [115625,165625) interp2 rows.

__device__ inline int item_seg(int t, const int* __restrict__ ei0,
                               const int* __restrict__ ei1, const int* __restrict__ ei2,
                               const int* __restrict__ A1r, const int* __restrict__ A2r) {
    if (t < NE0) return ei0[NE0 + t];
    if (t < NE0 + NE1) return 50000 + ei1[NE1 + (t - NE0)];
    if (t < EDGE_TOT) return 62500 + ei2[NE2 + (t - (NE0 + NE1))];
    if (t < EDGE_TOT + NNZ) return NT + A1r[t - EDGE_TOT];
    return NT + N0 + A2r[t - (EDGE_TOT + NNZ)];
}

// A: per-block bucket histogram -> hist_g[bucket*NBLK + blk]
__global__ __launch_bounds__(256) void bin_hist(const int* __restrict__ ei0,
        const int* __restrict__ ei1, const int* __restrict__ ei2,
        const int* __restrict__ A1r, const int* __restrict__ A2r,
        int* __restrict__ hist_g) {
    __shared__ int h[NBUCK];
    for (int i = threadIdx.x; i < NBUCK; i += 256) h[i] = 0;
    __syncthreads();
    int base = blockIdx.x * 4096;
#pragma unroll
    for (int q = 0; q < 16; q++) {
        int t = base + q * 256 + threadIdx.x;
        if (t < ITEM_TOT) atomicAdd(&h[item_seg(t, ei0, ei1, ei2, A1r, A2r) >> 9], 1);
    }
    __syncthreads();
    for (int i = threadIdx.x; i < NBUCK; i += 256) hist_g[i * NBLK + blockIdx.x] = h[i];
}

// B1: bucket totals
__global__ void bucket_tot_k(const int* __restrict__ hist_g, int* __restrict__ btot) {
    int b = blockIdx.x;
    int s = 0;
    for (int i = threadIdx.x; i < NBLK; i += 64) s += hist_g[b * NBLK + i];
#pragma unroll
    for (int o = 32; o > 0; o >>= 1) s += __shfl_down(s, o, 64);
    if (threadIdx.x == 0) btot[b] = s;
}

// B3: per-bucket exclusive scan of hist_g row + bucket_base
__global__ void hist_scan(int* __restrict__ hist_g, const int* __restrict__ btot,
                          int* __restrict__ bbase) {
    int b = blockIdx.x, lane = threadIdx.x;
    int s = 0;
    for (int j = lane; j < b; j += 64) s += btot[j];
#pragma unroll
    for (int o = 32; o > 0; o >>= 1) s += __shfl_down(s, o, 64);
    int base = __shfl(s, 0, 64);
    if (lane == 0) {
        bbase[b] = base;
        if (b == NBUCK - 1) bbase[NBUCK] = ITEM_TOT;
    }
    int v[6], ts = 0;
#pragma unroll
    for (int q = 0; q < 6; q++) {
        int i = lane * 6 + q;
        v[q] = (i < NBLK) ? hist_g[b * NBLK + i] : 0;
        ts += v[q];
    }
    int sc = ts;
#pragma unroll
    for (int o = 1; o < 64; o <<= 1) {
        int t2 = __shfl_up(sc, o, 64);
        if (lane >= o) sc += t2;
    }
    int run = base + sc - ts;
#pragma unroll
    for (int q = 0; q < 6; q++) {
        int i = lane * 6 + q;
        if (i < NBLK) hist_g[b * NBLK + i] = run;
        run += v[q];
    }
}

// C: scatter items into bucket-ordered packed array
__global__ __launch_bounds__(256) void bin_scatter(const int* __restrict__ ei0,
        const int* __restrict__ ei1, const int* __restrict__ ei2,
        const int* __restrict__ A1r, const int* __restrict__ A1c, const float* __restrict__ A1v,
        const int* __restrict__ A2r, const int* __restrict__ A2c, const float* __restrict__ A2v,
        const int* __restrict__ hist_g, int* __restrict__ bpacked, float* __restrict__ bval) {
    __shared__ int cur[NBUCK];
    for (int i = threadIdx.x; i < NBUCK; i += 256) cur[i] = hist_g[i * NBLK + blockIdx.x];
    __syncthreads();
    int base = blockIdx.x * 4096;
#pragma unroll
    for (int q = 0; q < 16; q++) {
        int t = base + q * 256 + threadIdx.x;
        if (t >= ITEM_TOT) continue;
        int seg, pay;
        float val = 0.f;
        bool isv = false;
        if (t < NE0) { seg = ei0[NE0 + t]; pay = ei0[t]; }
        else if (t < NE0 + NE1) { int e = t - NE0; seg = 50000 + ei1[NE1 + e]; pay = ei1[e]; }
        else if (t < EDGE_TOT) { int e = t - (NE0 + NE1); seg = 62500 + ei2[NE2 + e]; pay = ei2[e]; }
        else if (t < EDGE_TOT + NNZ) { int k = t - EDGE_TOT; seg = NT + A1r[k]; pay = A1c[k]; val = A1v[k]; isv = true; }
        else { int k = t - (EDGE_TOT + NNZ); seg = NT + N0 + A2r[k]; pay = A2c[k]; val = A2v[k]; isv = true; }
        int bk = seg >> 9;
        int p = atomicAdd(&cur[bk], 1);
        bpacked[p] = ((seg - (bk << 9)) << 16) | pay;  // seg_local<512, pay<65536
        if (isv) bval[p] = val;
    }
}

// E: per-bucket count + scan + fill; writes offs[seg]=start directly.
__global__ __launch_bounds__(256) void bucket_fill(const int* __restrict__ bpacked,
        const float* __restrict__ bval, const int* __restrict__ bbase,
        int* __restrict__ offs, int* __restrict__ csrc, float* __restrict__ cval) {
    __shared__ int cnt[SPB];
    __shared__ int wsum2[4];
    int b = blockIdx.x, tid = threadIdx.x;
    int segbase = b * SPB;
    int seglim = SEG_TOT - segbase;
    if (seglim > SPB) seglim = SPB;
    int ibeg = bbase[b], iend = bbase[b + 1];
    for (int i = tid; i < SPB; i += 256) cnt[i] = 0;
    __syncthreads();
    for (int i = ibeg + tid; i < iend; i += 256)
        atomicAdd(&cnt[bpacked[i] >> 16], 1);
    __syncthreads();
    int lane = tid & 63, wid = tid >> 6;
    int v0 = cnt[tid * 2], v1 = cnt[tid * 2 + 1];
    int ts = v0 + v1, sc = ts;
#pragma unroll
    for (int o = 1; o < 64; o <<= 1) {
        int t2 = __shfl_up(sc, o, 64);
        if (lane >= o) sc += t2;
    }
    if (lane == 63) wsum2[wid] = sc;
    __syncthreads();
    int woff = 0;
    for (int w = 0; w < wid; w++) woff += wsum2[w];
    int ex = ibeg + woff + sc - ts;  // start position of seg tid*2
    __syncthreads();
    cnt[tid * 2] = ex;
    cnt[tid * 2 + 1] = ex + v0;
    if (tid * 2 < seglim) offs[segbase + tid * 2] = ex;
    if (tid * 2 + 1 < seglim) offs[segbase + tid * 2 + 1] = ex + v0;
    if (b == NBUCK - 1 && tid == 0) offs[SEG_TOT] = ITEM_TOT;
    __syncthreads();
    for (int i = ibeg + tid; i < iend; i += 256) {
        int w2 = bpacked[i];
        int sl = w2 >> 16, pay = w2 & 0xffff;
        int p = atomicAdd(&cnt[sl], 1);
        csrc[p] = pay;
        if (segbase + sl >= NT) cval[p - EDGE_TOT] = bval[i];
    }
}

// ================= batched gathers =================
// segment n spans [offs[n], offs[n+1])

__global__ void gather6_b(const float* __restrict__ x0, const float* __restrict__ x1,
                          const float* __restrict__ x2, const int* __restrict__ offs,
                          const int* __restrict__ csrc, float* __restrict__ agg6) {
    int n = blockIdx.x * blockDim.x + threadIdx.x;
    if (n >= NT) return;
    const float* x = (n < 50000) ? x0 : (n < 62500 ? x1 : x2);
    float a0 = 0, a1 = 0, a2 = 0, a3 = 0, a4 = 0, a5 = 0;
    int b = offs[n], e = offs[n + 1];
    for (int j = b; j < e; j++) {
        const float* p = x + (size_t)csrc[j] * 6;
        a0 += p[0]; a1 += p[1]; a2 += p[2]; a3 += p[3]; a4 += p[4]; a5 += p[5];
    }
    float* o = agg6 + (size_t)n * 6;
    o[0] = a0; o[1] = a1; o[2] = a2; o[3] = a3; o[4] = a4; o[5] = a5;
}

// reads bf16 hi plane only: 256 B/edge instead of 512
__global__ __launch_bounds__(256) void gatherH_b(const unsigned short* __restrict__ h1hi,
                                                 const int* __restrict__ offs,
                                                 const int* __restrict__ csrc,
                                                 float* __restrict__ agg) {
    int t = blockIdx.x * blockDim.x + threadIdx.x;
    int n = t >> 5, g = t & 31;
    if (n >= NT) return;
    int nb = (n < 50000) ? 0 : (n < 62500 ? 50000 : 62500);
    float4 a = {0.f, 0.f, 0.f, 0.f};
    int b = offs[n], e = offs[n + 1];
    for (int j = b; j < e; j++) {
        uint2 u = *(const uint2*)(h1hi + (size_t)(nb + csrc[j]) * 128 + g * 4);
        a.x += __uint_as_float(u.x << 16);
        a.y += __uint_as_float(u.x & 0xffff0000u);
        a.z += __uint_as_float(u.y << 16);
        a.w += __uint_as_float(u.y & 0xffff0000u);
    }
    ((float4*)(agg + (size_t)n * 128))[g] = a;
}

__global__ __launch_bounds__(256) void interp_b(const float* __restrict__ ecat,
                                                const int* __restrict__ offs,
                                                const int* __restrict__ csrc,
                                                const float* __restrict__ cval,
                                                float* __restrict__ i1, float* __restrict__ i2) {
    int t = blockIdx.x * blockDim.x + threadIdx.x;
    int ng = t / 24, g = t % 24;
    if (ng >= 2 * N0) return;
    int a = (ng >= N0) ? 1 : 0;
    int nl = ng - a * N0;
    const float* e = ecat + (size_t)(a ? 62500 : 50000) * 96;
    float* ob = a ? i2 : i1;
    int seg = NT + ng;
    float4 s = {0.f, 0.f, 0.f, 0.f};
    int b = offs[seg], en = offs[seg + 1];
    for (int j = b; j < en; j++) {
        int c = csrc[j];
        float v = cval[j - EDGE_TOT];
        float4 w = ((const float4*)(e + (size_t)c * 96))[g];
        s.x += v * w.x; s.y += v * w.y; s.z += v * w.z; s.w += v * w.w;
    }
    ((float4*)(ob + (size_t)nl * 96))[g] = s;
}

// ================= weight preconvert =================
__global__ void conv_weights(const float* __restrict__ c2Wrel, const float* __restrict__ c2Wroot,
                             const float* __restrict__ linW, const float* __restrict__ dW0,
                             unsigned short* __restrict__ c2hi, unsigned short* __restrict__ c2lo,
                             unsigned short* __restrict__ lhi, unsigned short* __restrict__ llo,
                             float* __restrict__ decWt) {
    int t = blockIdx.x * blockDim.x + threadIdx.x;
    if (t < 98304) {
        int i = t / 32768, r = t % 32768;
        int n = r / 256, k = r % 256;
        float w = (k < 128) ? c2Wrel[i * 16384 + k * 128 + n]
                            : c2Wroot[i * 16384 + (k - 128) * 128 + n];
        unsigned short hi, lo;
        split_bf16(w, hi, lo);
        c2hi[t] = hi; c2lo[t] = lo;
    } else if (t < 135168) {
        int u = t - 98304;
        int i = u / 12288, r = u % 12288;
        int n = r / 128, k = r % 128;
        unsigned short hi, lo;
        split_bf16(linW[i * 12288 + k * 96 + n], hi, lo);
        lhi[u] = hi; llo[u] = lo;
    } else if (t < 153600) {
        int u = t - 135168;
        int chn = u / 6144, r = u % 6144;
        int col = r / 96, k = r % 96;
        decWt[u] = dW0[chn * 6144 + k * 64 + col];
    }
}

// ================= conv1 (fp32, K=12) -> writes h1 as bf16 hi/lo planes ====
__global__ __launch_bounds__(256) void conv1_b(
        const float* __restrict__ agg6, const float* __restrict__ x0,
        const float* __restrict__ x1, const float* __restrict__ x2,
        const float* __restrict__ Wrel, const float* __restrict__ Wroot,
        const float* __restrict__ brel,
        unsigned short* __restrict__ h1hi, unsigned short* __restrict__ h1lo) {
    __shared__ float As[16][65];
    __shared__ float Ws[16][64];
    int bx = blockIdx.x;
    int l, lbk;
    if (bx < 782) { l = 0; lbk = bx; }
    else if (bx < 978) { l = 1; lbk = bx - 782; }
    else { l = 2; lbk = bx - 978; }
    int nb = (l == 0) ? 0 : (l == 1 ? 50000 : 62500);
    int M = (l == 0) ? N0 : (l == 1 ? N1 : N2);
    const float* xl = (l == 0) ? x0 : (l == 1 ? x1 : x2);
    const float* A1 = agg6 + (size_t)nb * 6;
    const float* W1 = Wrel + l * 768;
    const float* W2 = Wroot + l * 768;
    const float* bias = brel + l * 128;
    int m0 = lbk * 64, n0 = blockIdx.y * 64;
    int tid = threadIdx.x;
    int tm = tid >> 4, tn = tid & 15;
    float acc[4][4] = {};
#pragma unroll
    for (int q = 0; q < 4; q++) {
        int idx = tid + q * 256;
        int row = idx >> 4, kk = idx & 15;
        int m = m0 + row;
        float v = 0.f;
        if (m < M && kk < 12)
            v = (kk < 6) ? A1[(size_t)m * 6 + kk] : xl[(size_t)m * 6 + kk - 6];
        As[kk][row] = v;
    }
#pragma unroll
    for (int q = 0; q < 4; q++) {
        int idx = tid + q * 256;
        int kk = idx >> 6, nn2 = idx & 63;
        float v = 0.f;
        if (kk < 12)
            v = (kk < 6) ? W1[kk * 128 + n0 + nn2] : W2[(kk - 6) * 128 + n0 + nn2];
        Ws[kk][nn2] = v;
    }
    __syncthreads();
#pragma unroll
    for (int k = 0; k < 12; k++) {
        float av[4], wv[4];
#pragma unroll
        for (int i = 0; i < 4; i++) av[i] = As[k][tm * 4 + i];
#pragma unroll
        for (int j = 0; j < 4; j++) wv[j] = Ws[k][tn * 4 + j];
#pragma unroll
        for (int i = 0; i < 4; i++)
#pragma unroll
            for (int j = 0; j < 4; j++) acc[i][j] += av[i] * wv[j];
    }
#pragma unroll
    for (int i = 0; i < 4; i++) {
        int m = m0 + tm * 4 + i;
        if (m >= M) continue;
        unsigned short hs[4], ls[4];
#pragma unroll
        for (int j = 0; j < 4; j++) {
            float v = fmaxf(acc[i][j] + bias[n0 + tn * 4 + j], 0.f);
            split_bf16(v, hs[j], ls[j]);
        }
        uint2 ph = {(unsigned)hs[0] | ((unsigned)hs[1] << 16),
                    (unsigned)hs[2] | ((unsigned)hs[3] << 16)};
        uint2 pl = {(unsigned)ls[0] | ((unsigned)ls[1] << 16),
                    (unsigned)ls[2] | ((unsigned)ls[3] << 16)};
        size_t off = (size_t)(nb + m) * 128 + n0 + tn * 4;
        *(uint2*)(h1hi + off) = ph;
        *(uint2*)(h1lo + off) = pl;
    }
}

// ================= fused conv2+lin (split-bf16 MFMA) =================
// phase1 A: kt<128 -> fp32 agg (runtime split); kt>=128 -> pre-split h1 planes.
__global__ __launch_bounds__(256) void conv2lin(
        const float* __restrict__ agg,
        const unsigned short* __restrict__ h1hi, const unsigned short* __restrict__ h1lo,
        const unsigned short* __restrict__ c2hi, const unsigned short* __restrict__ c2lo,
        const float* __restrict__ c2b,
        const unsigned short* __restrict__ lnhi, const unsigned short* __restrict__ lnlo,
        const float* __restrict__ lnb, float* __restrict__ ecat) {
    __shared__ unsigned short smem[25088];  // 50.2 KB union
    unsigned short* Ah = smem;              // 64*40
    unsigned short* Al = smem + 2560;
    unsigned short* Bh = smem + 5120;       // 128*40
    unsigned short* Bl = smem + 10240;
    unsigned short* Hh = smem;              // 64*136 (phase 2)
    unsigned short* Hl = smem + 8704;
    unsigned short* B2h = smem + 17408;     // 96*40
    unsigned short* B2l = smem + 21248;
    const int LDA = 40;

    int bx = blockIdx.x;
    int l, lbk;
    if (bx < 782) { l = 0; lbk = bx; }
    else if (bx < 978) { l = 1; lbk = bx - 782; }
    else { l = 2; lbk = bx - 978; }
    int nb = (l == 0) ? 0 : (l == 1 ? 50000 : 62500);
    int M = (l == 0) ? N0 : (l == 1 ? N1 : N2);
    const float* A1 = agg + (size_t)nb * 128;
    const unsigned short* A2h = h1hi + (size_t)nb * 128;
    const unsigned short* A2l = h1lo + (size_t)nb * 128;
    const unsigned short* W1h = c2hi + l * 32768;
    const unsigned short* W1l = c2lo + l * 32768;
    const float* b1 = c2b + l * 128;
    const unsigned short* W2h = lnhi + l * 12288;
    const unsigned short* W2l = lnlo + l * 12288;
    const float* b2 = lnb + l * 96;
    float* C = ecat + (size_t)nb * 96;
    int m0 = lbk * 64;

    int tid = threadIdx.x;
    int lane = tid & 63, wid = tid >> 6;
    int waveM = wid & 1, waveN = wid >> 1;
    int l15 = lane & 15, quad = lane >> 4;
    int arow = tid >> 2, acol = (tid & 3) * 8;
    int brow = tid >> 1, bcol = (tid & 1) * 16;

    floatx4 acc[2][4];
#pragma unroll
    for (int i = 0; i < 2; i++)
#pragma unroll
        for (int j = 0; j < 4; j++) acc[i][j] = (floatx4){0.f, 0.f, 0.f, 0.f};

    // ---- phase 1: K=256 ----
    for (int kt = 0; kt < 256; kt += 32) {
        __syncthreads();
        {
            int m = m0 + arow;
            ushort8 hv, lv;
            if (m < M) {
                int kg = kt + acol;
                if (kg < 128) {  // uniform per kt (kt<128 => kg<=120)
                    const float* src = A1 + (size_t)m * 128 + kg;
                    float4 u0 = *(const float4*)src;
                    float4 u1 = *(const float4*)(src + 4);
                    float xv[8] = {u0.x, u0.y, u0.z, u0.w, u1.x, u1.y, u1.z, u1.w};
#pragma unroll
                    for (int q = 0; q < 8; q++) {
                        unsigned short h, lo2;
                        split_bf16(xv[q], h, lo2);
                        hv[q] = h; lv[q] = lo2;
                    }
                } else {
                    size_t off = (size_t)m * 128 + (kg - 128);
                    hv = *(const ushort8*)(A2h + off);
                    lv = *(const ushort8*)(A2l + off);
                }
            } else {
                hv = (ushort8)0; lv = (ushort8)0;
            }
            *(ushort8*)(&Ah[arow * LDA + acol]) = hv;
            *(ushort8*)(&Al[arow * LDA + acol]) = lv;
        }
        {
            const unsigned short* ph = W1h + (size_t)brow * 256 + kt + bcol;
            const unsigned short* pl = W1l + (size_t)brow * 256 + kt + bcol;
            *(ushort8*)(&Bh[brow * LDA + bcol]) = *(const ushort8*)ph;
            *(ushort8*)(&Bh[brow * LDA + bcol + 8]) = *(const ushort8*)(ph + 8);
            *(ushort8*)(&Bl[brow * LDA + bcol]) = *(const ushort8*)pl;
            *(ushort8*)(&Bl[brow * LDA + bcol + 8]) = *(const ushort8*)(pl + 8);
        }
        __syncthreads();
        short8 af[2][2];
#pragma unroll
        for (int mt = 0; mt < 2; mt++) {
            int r = waveM * 32 + mt * 16 + l15;
            af[mt][0] = *(const short8*)(&Ah[r * LDA + quad * 8]);
            af[mt][1] = *(const short8*)(&Al[r * LDA + quad * 8]);
        }
#pragma unroll
        for (int nt = 0; nt < 4; nt++) {
            int c = waveN * 64 + nt * 16 + l15;
            short8 bh = *(const short8*)(&Bh[c * LDA + quad * 8]);
            short8 bl = *(const short8*)(&Bl[c * LDA + quad * 8]);
#pragma unroll
            for (int mt = 0; mt < 2; mt++) {
                acc[mt][nt] = __builtin_amdgcn_mfma_f32_16x16x32_bf16(af[mt][0], bh, acc[mt][nt], 0, 0, 0);
                acc[mt][nt] = __builtin_amdgcn_mfma_f32_16x16x32_bf16(af[mt][0], bl, acc[mt][nt], 0, 0, 0);
                acc[mt][nt] = __builtin_amdgcn_mfma_f32_16x16x32_bf16(af[mt][1], bh, acc[mt][nt], 0, 0, 0);
            }
        }
    }

    // ---- transition: h2 tile -> LDS hi/lo ----
    __syncthreads();
    {
        float bs1[4];
#pragma unroll
        for (int nt = 0; nt < 4; nt++) bs1[nt] = b1[waveN * 64 + nt * 16 + l15];
#pragma unroll
        for (int mt = 0; mt < 2; mt++)
#pragma unroll
            for (int nt = 0; nt < 4; nt++)
#pragma unroll
                for (int r = 0; r < 4; r++) {
                    int row = waveM * 32 + mt * 16 + quad * 4 + r;
                    int col = waveN * 64 + nt * 16 + l15;
                    float v = fmaxf(acc[mt][nt][r] + bs1[nt], 0.f);
                    unsigned short h, lo2;
                    split_bf16(v, h, lo2);
                    Hh[row * 136 + col] = h;
                    Hl[row * 136 + col] = lo2;
                }
    }

    // ---- phase 2: K=128, J=96 ----
    floatx4 acc2[2][3];
#pragma unroll
    for (int i = 0; i < 2; i++)
#pragma unroll
        for (int j = 0; j < 3; j++) acc2[i][j] = (floatx4){0.f, 0.f, 0.f, 0.f};

    for (int kt = 0; kt < 128; kt += 32) {
        __syncthreads();
        if (brow < 96) {
            const unsigned short* ph = W2h + (size_t)brow * 128 + kt + bcol;
            const unsigned short* pl = W2l + (size_t)brow * 128 + kt + bcol;
            *(ushort8*)(&B2h[brow * LDA + bcol]) = *(const ushort8*)ph;
            *(ushort8*)(&B2h[brow * LDA + bcol + 8]) = *(const ushort8*)(ph + 8);
            *(ushort8*)(&B2l[brow * LDA + bcol]) = *(const ushort8*)pl;
            *(ushort8*)(&B2l[brow * LDA + bcol + 8]) = *(const ushort8*)(pl + 8);
        }
        __syncthreads();
        short8 af2[2][2];
#pragma unroll
        for (int mt = 0; mt < 2; mt++) {
            int r = waveM * 32 + mt * 16 + l15;
            af2[mt][0] = *(const short8*)(&Hh[r * 136 + kt + quad * 8]);
            af2[mt][1] = *(const short8*)(&Hl[r * 136 + kt + quad * 8]);
        }
#pragma unroll
        for (int nt = 0; nt < 3; nt++) {
            int c = waveN * 48 + nt * 16 + l15;
            short8 bh = *(const short8*)(&B2h[c * LDA + quad * 8]);
            short8 bl = *(const short8*)(&B2l[c * LDA + quad * 8]);
#pragma unroll
            for (int mt = 0; mt < 2; mt++) {
                acc2[mt][nt] = __builtin_amdgcn_mfma_f32_16x16x32_bf16(af2[mt][0], bh, acc2[mt][nt], 0, 0, 0);
                acc2[mt][nt] = __builtin_amdgcn_mfma_f32_16x16x32_bf16(af2[mt][0], bl, acc2[mt][nt], 0, 0, 0);
                acc2[mt][nt] = __builtin_amdgcn_mfma_f32_16x16x32_bf16(af2[mt][1], bh, acc2[mt][nt], 0, 0, 0);
            }
        }
    }

    // ---- epilogue ----
    float bs2[3];
#pragma unroll
    for (int nt = 0; nt < 3; nt++) bs2[nt] = b2[waveN * 48 + nt * 16 + l15];
#pragma unroll
    for (int mt = 0; mt < 2; mt++)
#pragma unroll
        for (int r = 0; r < 4; r++) {
            int grow = m0 + waveM * 32 + mt * 16 + quad * 4 + r;
            if (grow >= M) continue;
#pragma unroll
            for (int nt = 0; nt < 3; nt++) {
                int col = waveN * 48 + nt * 16 + l15;
                C[(size_t)grow * 96 + col] = acc2[mt][nt][r] + bs2[nt];
            }
        }
}

// ================= MFMA decoder =================
__global__ __launch_bounds__(256) void decoder_mfma(
        const float* __restrict__ e0, const float* __restrict__ i1,
        const float* __restrict__ i2, const float* __restrict__ decWt,
        const float* __restrict__ b0, const float* __restrict__ Wout,
        const float* __restrict__ bout, float* __restrict__ out, int N) {
    __shared__ float As[6400];   // [row][k], pitch 100
    __shared__ float Bs[6400];   // [col][k], pitch 100
    __shared__ float red[64][2];
    __shared__ float sb0[64], sWo[64];
    int ch = blockIdx.y;
    int tid = threadIdx.x;
    int m0 = blockIdx.x * 64;

    for (int idx = tid; idx < 1536; idx += 256) {
        int col = idx / 24, k0 = (idx % 24) * 4;
        *(float4*)(&Bs[col * 100 + k0]) = *(const float4*)(decWt + ch * 6144 + col * 96 + k0);
    }
    if (tid < 64) { sb0[tid] = b0[ch * 64 + tid]; sWo[tid] = Wout[ch * 64 + tid]; }
    for (int idx = tid; idx < 1536; idx += 256) {
        int row = idx / 24, k0 = (idx % 24) * 4;
        int m = m0 + row;
        float4 v = {0.f, 0.f, 0.f, 0.f};
        if (m < N) {
            const float* base = (k0 < 32) ? e0 : (k0 < 64 ? i1 : i2);
            v = *(const float4*)(base + (size_t)m * 96 + ch * 32 + (k0 & 31));
        }
        *(float4*)(&As[row * 100 + k0]) = v;
    }
    __syncthreads();

    int lane = tid & 63, wid = tid >> 6;
    int waveM = wid & 1, waveN = wid >> 1;
    int l15 = lane & 15, quad = lane >> 4;
    floatx4 acc[2][2];
#pragma unroll
    for (int i = 0; i < 2; i++)
#pragma unroll
        for (int j = 0; j < 2; j++) acc[i][j] = (floatx4){0.f, 0.f, 0.f, 0.f};

#pragma unroll
    for (int kt = 0; kt < 96; kt += 32) {
        short8 ah[2], al[2];
#pragma unroll
        for (int mt = 0; mt < 2; mt++) {
            int r = waveM * 32 + mt * 16 + l15;
            split8(&As[r * 100 + kt + quad * 8], ah[mt], al[mt]);
        }
#pragma unroll
        for (int nt = 0; nt < 2; nt++) {
            int c = waveN * 32 + nt * 16 + l15;
            short8 bh, bl;
            split8(&Bs[c * 100 + kt + quad * 8], bh, bl);
#pragma unroll
            for (int mt = 0; mt < 2; mt++) {
                acc[mt][nt] = __builtin_amdgcn_mfma_f32_16x16x32_bf16(ah[mt], bh, acc[mt][nt], 0, 0, 0);
                acc[mt][nt] = __builtin_amdgcn_mfma_f32_16x16x32_bf16(ah[mt], bl, acc[mt][nt], 0, 0, 0);
                acc[mt][nt] = __builtin_amdgcn_mfma_f32_16x16x32_bf16(al[mt], bh, acc[mt][nt], 0, 0, 0);
            }
        }
    }

    float cb0[2], cwo[2];
#pragma unroll
    for (int nt = 0; nt < 2; nt++) {
        int col = waveN * 32 + nt * 16 + l15;
        cb0[nt] = sb0[col]; cwo[nt] = sWo[col];
    }
    float p[2][4];
#pragma unroll
    for (int mt = 0; mt < 2; mt++)
#pragma unroll
        for (int r = 0; r < 4; r++) {
            float s = 0.f;
#pragma unroll
            for (int nt = 0; nt < 2; nt++) {
                float h = acc[mt][nt][r] + cb0[nt];
                h = h > 0.f ? h : (expf(h) - 1.0f);
                s += h * cwo[nt];
            }
            p[mt][r] = s;
        }
#pragma unroll
    for (int mt = 0; mt < 2; mt++)
#pragma unroll
        for (int r = 0; r < 4; r++) {
#pragma unroll
            for (int msk = 1; msk < 16; msk <<= 1)
                p[mt][r] += __shfl_xor(p[mt][r], msk, 64);
        }
    if (l15 == 0) {
#pragma unroll
        for (int mt = 0; mt < 2; mt++)
#pragma unroll
            for (int r = 0; r < 4; r++) {
                int row = waveM * 32 + mt * 16 + quad * 4 + r;
                red[row][waveN] = p[mt][r];
            }
    }
    __syncthreads();
    if (tid < 64) {
        int m = m0 + tid;
        if (m < N) out[(size_t)m * 3 + ch] = red[tid][0] + red[tid][1] + bout[ch];
    }
}

// ================= host launch =================

extern "C" void kernel_launch(void* const* d_in, const int* in_sizes, int n_in,
                              void* d_out, int out_size, void* d_ws, size_t ws_size,
                              hipStream_t stream) {
    const float* x0 = (const float*)d_in[0];
    const float* x1 = (const float*)d_in[1];
    const float* x2 = (const float*)d_in[2];
    const int* ei0 = (const int*)d_in[3];
    const int* ei1 = (const int*)d_in[4];
    const int* ei2 = (const int*)d_in[5];
    const int* A1r = (const int*)d_in[6];
    const int* A1c = (const int*)d_in[7];
    const float* A1v = (const float*)d_in[8];
    const int* A2r = (const int*)d_in[9];
    const int* A2c = (const int*)d_in[10];
    const float* A2v = (const float*)d_in[11];
    const float* c1Wrel = (const float*)d_in[12];
    const float* c1brel = (const float*)d_in[13];
    const float* c1Wroot = (const float*)d_in[14];
    const float* c2Wrel = (const float*)d_in[15];
    const float* c2brel = (const float*)d_in[16];
    const float* c2Wroot = (const float*)d_in[17];
    const float* linW = (const float*)d_in[18];
    const float* linb = (const float*)d_in[19];
    const float* dW0 = (const float*)d_in[20];
    const float* db0 = (const float*)d_in[21];
    const float* dWout = (const float*)d_in[22];
    const float* dbout = (const float*)d_in[23];
    float* out = (float*)d_out;

    // ---- workspace (float words) ----
    float* ws = (float*)d_ws;
    float* agg6 = ws;                            // [0, 400,000)
    unsigned short* h1hi = (unsigned short*)(ws + 400000);   // 8.4M ushorts -> [400000, 4,600,000)
    unsigned short* h1lo = (unsigned short*)(ws + 4600000);  // 8.4M ushorts -> [4,600,000, 8,800,000)
    float* aggH = ws + 8800000;                  // 8.4M words [8.8M, 17.2M)
    float* ecat = ws + 17200000;                 // 6.3M words [17.2M, 23.5M)
    float* i1 = aggH;                            // overlay (dead after conv2lin)
    float* i2 = ws + 400000;                     // overlay h1 planes (dead after conv2lin)
    // binned intermediates overlay aggH (dead before gatherH writes aggH)
    int* bpacked = (int*)(ws + 8800000);         // 1,450,000
    float* bval = ws + 8800000 + 1450000;        // 1,450,000 (ends 11.7M < 17.2M)
    int* hist_g = (int*)(ws + 23500000);         // NBUCK*NBLK = 115,020
    int* btot = (int*)(ws + 23615020);           // 324
    int* bbase = (int*)(ws + 23615344);          // 325
    int* offs = (int*)(ws + 23665632);           // 165,626
    int* csrc = (int*)(ws + 23831264);           // 1,450,000
    float* cval = ws + 25281392;                 // 400,000
    unsigned short* c2hi = (unsigned short*)(ws + 25681392); // 98,304 ushort
    unsigned short* c2lo = c2hi + 98304;
    unsigned short* lnhi = c2lo + 98304;                     // 36,864 ushort
    unsigned short* lnlo = lnhi + 36864;
    float* decWt = ws + 25681392 + 135168;       // 18,432 floats; ends ~25,834,992 (~103.3 MB)

    conv_weights<<<(153600 + 255) / 256, 256, 0, stream>>>(
        c2Wrel, c2Wroot, linW, dW0, c2hi, c2lo, lnhi, lnlo, decWt);

    // ---- binned CSR build ----
    bin_hist<<<NBLK, 256, 0, stream>>>(ei0, ei1, ei2, A1r, A2r, hist_g);
    bucket_tot_k<<<NBUCK, 64, 0, stream>>>(hist_g, btot);
    hist_scan<<<NBUCK, 64, 0, stream>>>(hist_g, btot, bbase);
    bin_scatter<<<NBLK, 256, 0, stream>>>(ei0, ei1, ei2, A1r, A1c, A1v,
                                          A2r, A2c, A2v, hist_g, bpacked, bval);
    bucket_fill<<<NBUCK, 256, 0, stream>>>(bpacked, bval, bbase, offs, csrc, cval);

    // ---- encoder ----
    gather6_b<<<(NT + 255) / 256, 256, 0, stream>>>(x0, x1, x2, offs, csrc, agg6);
    dim3 g1(1027, 2);
    conv1_b<<<g1, 256, 0, stream>>>(agg6, x0, x1, x2, c1Wrel, c1Wroot, c1brel, h1hi, h1lo);
    gatherH_b<<<((size_t)NT * 32 + 255) / 256, 256, 0, stream>>>(h1hi, offs, csrc, aggH);
    conv2lin<<<1027, 256, 0, stream>>>(aggH, h1hi, h1lo, c2hi, c2lo, c2brel,
                                       lnhi, lnlo, linb, ecat);

    // ---- interpolation (writes i1 over aggH, i2 over h1 planes — both dead) ----
    interp_b<<<((size_t)2 * N0 * 24 + 255) / 256, 256, 0, stream>>>(
        ecat, offs, csrc, cval, i1, i2);

    // ---- decoder ----
    dim3 gd(782, 3);
    decoder_mfma<<<gd, 256, 0, stream>>>(ecat, i1, i2, decWt, db0, dWout, dbout, out, N0);
}